// Round 7
// baseline (517.164 us; speedup 1.0000x reference)
//
#include <hip/hip_runtime.h>
#include <hip/hip_bf16.h>

#define B_   64
#define N_   512
#define M_   512
#define Dm_  64
#define BIGF 1e30f
// gamma = 0.1; scaled units R' = R / (gamma*ln2):
//   r' = d' + mn' - log2(2^(mn'-a') + 2^(mn'-b') + 2^(mn'-c'))
#define SINV 14.426950408889634f    // 1/(gamma*ln2)
#define LAG  8                      // inter-wave lag = barrier period
#define RING 32                     // ring slots per boundary (read age 9, write win 8)
#define SPAD 1080                   // 135*8 steps; max live s = 1078
#define CH   4                      // chains (batches) per block

// Raw transcendental instructions (bypass OCML wrapper fixup code).
#if __has_builtin(__builtin_amdgcn_exp2f)
#define EXP2F(x) __builtin_amdgcn_exp2f(x)
#else
#define EXP2F(x) exp2f(x)
#endif
#if __has_builtin(__builtin_amdgcn_logf)
#define LOG2F(x) __builtin_amdgcn_logf(x)   // v_log_f32 computes log2
#else
#define LOG2F(x) __log2f(x)
#endif

// ---------------------------------------------------------------------------
// Kernel A: skewed bf16 distance matrix with LDS-staged coalesced stores.
//   Ds[b][s][t] = bf16( SINV * ||x[b,t,:] - y[b,s-sk(t),:]||^2 ),
//   sk(t) = t + (t>>6)*LAG.  Stores iterate output s-rows with contiguous t
//   (128 B/wave) instead of the naive 256-distinct-line scatter.
// ---------------------------------------------------------------------------
__global__ __launch_bounds__(256) void dtw_dist_skew(const float* __restrict__ x,
                                                     const float* __restrict__ y,
                                                     __hip_bfloat16* __restrict__ Ds) {
  __shared__ float xs[128][65];
  __shared__ float ys[128][65];
  __shared__ __hip_bfloat16 sm[128][130];   // staged bf16 tile (il, jl)
  const int b  = blockIdx.z;
  const int i0 = blockIdx.y * 128;
  const int j0 = blockIdx.x * 128;
  const int tid = threadIdx.x;

  const float* xb = x + ((size_t)b * N_ + i0) * Dm_;
  const float* yb = y + ((size_t)b * M_ + j0) * Dm_;
#pragma unroll
  for (int r = 0; r < 8; ++r) {
    int v4 = tid + r * 256;
    int row = v4 >> 4, c4 = (v4 & 15) * 4;
    float4 xv = *(const float4*)(xb + (size_t)row * Dm_ + c4);
    float4 yv = *(const float4*)(yb + (size_t)row * Dm_ + c4);
    xs[row][c4 + 0] = xv.x; xs[row][c4 + 1] = xv.y;
    xs[row][c4 + 2] = xv.z; xs[row][c4 + 3] = xv.w;
    ys[row][c4 + 0] = yv.x; ys[row][c4 + 1] = yv.y;
    ys[row][c4 + 2] = yv.z; ys[row][c4 + 3] = yv.w;
  }
  __syncthreads();

  const int ty = tid >> 4, tx = tid & 15;
  float acc[8][8];
#pragma unroll
  for (int e = 0; e < 8; ++e)
#pragma unroll
    for (int f = 0; f < 8; ++f) acc[e][f] = 0.f;

#pragma unroll 4
  for (int k = 0; k < Dm_; ++k) {
    float xa[8], yv[8];
#pragma unroll
    for (int e = 0; e < 8; ++e) xa[e] = xs[ty * 8 + e][k];
#pragma unroll
    for (int f = 0; f < 8; ++f) yv[f] = ys[tx * 8 + f][k];
#pragma unroll
    for (int e = 0; e < 8; ++e)
#pragma unroll
      for (int f = 0; f < 8; ++f) {
        float t = xa[e] - yv[f];
        acc[e][f] = fmaf(t, t, acc[e][f]);
      }
  }

  // stage bf16 tile in LDS (RNE conversion preserved)
#pragma unroll
  for (int e = 0; e < 8; ++e)
#pragma unroll
    for (int f = 0; f < 8; ++f)
      sm[ty * 8 + e][tx * 8 + f] = __float2bfloat16(acc[e][f] * SINV);
  __syncthreads();

  // coalesced skewed store: tile rows split into 2 wave-halves, each with a
  // CONSTANT skew offset (sk(t) = t + 8*wv). For output row s, half h
  // contributes a contiguous t-window.
  const int W0 = i0 >> 6;
  const int Sbase = i0 + j0 + 8 * W0;       // smallest s touched by this tile
  __hip_bfloat16* base = Ds + (size_t)b * SPAD * N_;
  const int g = tid >> 6, lane = tid & 63;  // 4 groups x 64 lanes
  for (int pass = 0; pass < 66; ++pass) {
    const int v = pass * 4 + g;             // 0..263 (s-span of tile = 263)
    const int s = Sbase + v;
#pragma unroll
    for (int h = 0; h < 2; ++h) {
      const int u  = i0 + v - 8 * h;        // = s - j0 - 8*(W0+h)
      const int lo = max(i0 + 64 * h, u - 127);
      const int hi = min(i0 + 64 * h + 63, u);
      const int t  = lo + lane;
      if (t <= hi) base[(size_t)s * N_ + t] = sm[t - i0][u - t];
    }
  }
}

// ---------------------------------------------------------------------------
// Kernel B: skewed-pipeline DP, FOUR batches per block (16 blocks).
// Lane t owns row i=t+1 of each batch; step s computes column j = s-skew+1
// (skew = t + wave*LAG).
//   A = R'[i-1][j]   : lane t-1's r @ s-1 via DPP wave_shr:1
//   B = R'[i][j-1]   : own previous value (register)
//   C = R'[i-1][j-1] : lane t-1's r @ s-2 (previous A)
// Ring publish: values buffered in registers (SSA, free) and flushed by
// lane 63 of waves 0..6 once per epoch — nothing on the per-step chain.
// Read slot (s-9) mod 32 vs write window {s0..s0+7}: disjoint, 1+ epoch old.
// ---------------------------------------------------------------------------
__global__ __launch_bounds__(512) void dtw_dp4(const ushort* __restrict__ Ds,
                                               float* __restrict__ wv) {
  const int q    = blockIdx.x;        // 0..15
  const int b0   = q * CH;
  const int t    = threadIdx.x;       // 0..511
  const int w    = t >> 6;            // wave 0..7
  const int lane = t & 63;
  const int skew = t + w * LAG;       // max 511 + 56 = 567

  __shared__ float ring[CH * 8 * RING];   // row 7 of each chain stays BIGF
  for (int i2 = t; i2 < CH * 8 * RING; i2 += 512) ring[i2] = BIGF;
  __syncthreads();

  const ushort* col[CH];
#pragma unroll
  for (int c = 0; c < CH; ++c)
    col[c] = Ds + (size_t)(b0 + c) * SPAD * N_ + t;

  const int rdw  = ((w + 7) & 7) * RING;  // wave w reads row w-1 (w=0 -> 7: BIGF)
  const bool pub = (lane == 63) && (w < 7);
  const int wrw  = w * RING;

  float A[CH], Bv[CH], r[CH];
#pragma unroll
  for (int c = 0; c < CH; ++c) {
    A[c] = (t == 0) ? 0.0f : BIGF;   // becomes C = R'[0][0] = 0 at lane 0's step 0
    Bv[c] = BIGF;                    // R'[i][0] = BIG
    r[c] = BIGF;
  }

  float dc[CH][LAG];
#pragma unroll
  for (int c = 0; c < CH; ++c)
#pragma unroll
    for (int k = 0; k < LAG; ++k)
      dc[c][k] = __uint_as_float((uint)col[c][(size_t)k * N_] << 16);

  const int NBLK = SPAD / LAG;   // 135
  for (int blk = 0; blk < NBLK; ++blk) {
    const int s0 = blk * LAG;

    // issue next epoch's coalesced row loads (pinned before compute)
    ushort nx[CH][LAG];
#pragma unroll
    for (int c = 0; c < CH; ++c)
#pragma unroll
      for (int k = 0; k < LAG; ++k) {
        int sl = s0 + LAG + k; sl = sl > SPAD - 1 ? SPAD - 1 : sl;
        nx[c][k] = col[c][(size_t)sl * N_];
      }
    __builtin_amdgcn_sched_barrier(0);

    // ring values (uniform-address LDS broadcast), >=1 epoch old
    float rv[CH][LAG];
#pragma unroll
    for (int c = 0; c < CH; ++c)
#pragma unroll
      for (int k = 0; k < LAG; ++k)
        rv[c][k] = ring[c * 8 * RING + rdw + ((s0 + k - LAG - 1) & (RING - 1))];
    __builtin_amdgcn_sched_barrier(0);

    float rbuf[CH][LAG];
#pragma unroll
    for (int k = 0; k < LAG; ++k) {
      const int n = s0 + k - skew;
      const bool active = (unsigned)n < (unsigned)M_;   // shared by all chains
#pragma unroll
      for (int c = 0; c < CH; ++c) {
        const int nbi = __builtin_amdgcn_update_dpp(__float_as_int(rv[c][k]),
                        __float_as_int(r[c]), 0x138 /*wave_shr:1*/, 0xF, 0xF, false);
        const float nb = __int_as_float(nbi);
        const float Cv = A[c];               // R'[i-1][j-1]
        A[c] = nb;                           // R'[i-1][j]
        const float mn = fminf(fminf(nb, Bv[c]), Cv);
        const float ev = (EXP2F(mn - nb) + EXP2F(mn - Bv[c])) + EXP2F(mn - Cv);
        const float rr = (dc[c][k] + mn) - LOG2F(ev);
        r[c]  = active ? rr : BIGF;
        Bv[c] = active ? rr : Bv[c];
        rbuf[c][k] = r[c];                   // SSA rename, no real mov
      }
    }

    if (pub) {                               // one lane per wave, off the chain
#pragma unroll
      for (int c = 0; c < CH; ++c)
#pragma unroll
        for (int k = 0; k < LAG; ++k)
          ring[c * 8 * RING + wrw + ((s0 + k) & (RING - 1))] = rbuf[c][k];
    }
    __syncthreads();   // publishes ring; drains nx loads (issued 1 epoch ago)

#pragma unroll
    for (int c = 0; c < CH; ++c)
#pragma unroll
      for (int k = 0; k < LAG; ++k)
        dc[c][k] = __uint_as_float((uint)nx[c][k] << 16);
  }

  if (t == N_ - 1) {
#pragma unroll
    for (int c = 0; c < CH; ++c)
      wv[b0 + c] = EXP2F(-0.1f * Bv[c]);   // w = exp(-R) = 2^(-gamma*R')
  }
}

// ---------------------------------------------------------------------------
// Kernel C: out = x * w[b], full-grid elementwise (float4).
// ---------------------------------------------------------------------------
__global__ __launch_bounds__(256) void dtw_mul_kernel(const float* __restrict__ x,
                                                      const float* __restrict__ wv,
                                                      float* __restrict__ out) {
  const int idx = blockIdx.x * 256 + threadIdx.x;   // float4 index
  const int b = idx >> 13;                          // 8192 float4 per batch
  const float w = wv[b];
  float4 v = ((const float4*)x)[idx];
  v.x *= w; v.y *= w; v.z *= w; v.w *= w;
  ((float4*)out)[idx] = v;
}

// ---------------------------------------------------------------------------
// Fallback (no workspace): barrier-per-step fused DP. Slow but correct.
// ---------------------------------------------------------------------------
__global__ __launch_bounds__(512) void dtw_dp_fused(const float* __restrict__ x,
                                                    const float* __restrict__ y,
                                                    float* __restrict__ out) {
  __shared__ float v[3][516];
  const int b = blockIdx.x;
  const int t = threadIdx.x;
  const int i = t + 1;
  if (t == 0) { v[0][0] = 0.f; v[1][0] = BIGF; v[2][0] = BIGF; }
  v[0][i] = BIGF;
  v[1][i] = BIGF;
  float xr[Dm_];
  const float* xrow = x + ((size_t)b * N_ + t) * Dm_;
#pragma unroll
  for (int k = 0; k < Dm_; ++k) xr[k] = xrow[k];
  __syncthreads();
  int cur = 2, m1 = 1, m2 = 0;
  const float GLN2 = 0.069314718055994531f;
  for (int p = 2; p <= N_ + M_; ++p) {
    const int j = p - i;
    const bool valid = (j >= 1) && (j <= M_);
    float d = 0.f;
    if (valid) {
      const float* yr = y + ((size_t)b * M_ + (j - 1)) * Dm_;
      float a = 0.f;
#pragma unroll
      for (int k = 0; k < Dm_; ++k) { float u = xr[k] - yr[k]; a = fmaf(u, u, a); }
      d = a;
    }
    const float a  = v[m1][i - 1];
    const float bb = v[m1][i];
    const float c  = v[m2][i - 1];
    const float mn = fminf(fminf(a, bb), c);
    const float s = exp2f((mn - a) * SINV) + exp2f((mn - bb) * SINV) +
                    exp2f((mn - c) * SINV);
    const float rr = valid ? (d + mn - GLN2 * log2f(s)) : BIGF;
    v[cur][i] = rr;
    if (t == 0) v[cur][0] = BIGF;
    __syncthreads();
    const int tmp = m2; m2 = m1; m1 = cur; cur = tmp;
  }
  const float dist = v[(N_ + M_) % 3][N_];
  const float wsc = expf(-dist);
  const float* xb = x + (size_t)b * N_ * Dm_;
  float* ob = out + (size_t)b * N_ * Dm_;
#pragma unroll
  for (int e = 0; e < (N_ * Dm_) / 512; ++e) {
    const int idx = e * 512 + t;
    ob[idx] = xb[idx] * wsc;
  }
}

// ---------------------------------------------------------------------------
extern "C" void kernel_launch(void* const* d_in, const int* in_sizes, int n_in,
                              void* d_out, int out_size, void* d_ws, size_t ws_size,
                              hipStream_t stream) {
  const float* x = (const float*)d_in[0];
  const float* y = (const float*)d_in[1];
  float* out = (float*)d_out;

  const size_t needS = (size_t)B_ * SPAD * N_ * 2;   // 70,778,880 B
  const int mul_grid = (B_ * N_ * Dm_ / 4) / 256;    // 2048

  if (ws_size >= needS + 4096) {
    __hip_bfloat16* Dsb = (__hip_bfloat16*)d_ws;
    float* wvp = (float*)((char*)d_ws + needS);
    dim3 g(M_ / 128, N_ / 128, B_);
    dtw_dist_skew<<<g, dim3(256), 0, stream>>>(x, y, Dsb);
    dtw_dp4<<<dim3(B_ / CH), dim3(512), 0, stream>>>((const ushort*)Dsb, wvp);
    dtw_mul_kernel<<<dim3(mul_grid), dim3(256), 0, stream>>>(x, wvp, out);
  } else {
    dtw_dp_fused<<<dim3(B_), dim3(512), 0, stream>>>(x, y, out);
  }
}

// Round 8
// 222.627 us; speedup vs baseline: 2.3230x; 2.3230x over previous
//
#include <hip/hip_runtime.h>
#include <hip/hip_bf16.h>

#define B_   64
#define N_   512
#define M_   512
#define Dm_  64
#define BIGF 1e30f
#define BIGP 0x714A714Au            // 2x bf16(~1.01e30) packed
// gamma = 0.1; scaled units R' = R / (gamma*ln2):
//   r' = d' + mn' - log2(2^(mn'-a') + 2^(mn'-b') + 2^(mn'-c'))
#define SINV 14.426950408889634f    // 1/(gamma*ln2)
#define LAG  16                     // inter-wave lag = barrier period
#define RING 64                     // slots per boundary row (4 phases x 16)
#define SPAD 1136                   // step rows 0..1135; last live step = 1134

#if __has_builtin(__builtin_amdgcn_exp2f)
#define EXP2F(x) __builtin_amdgcn_exp2f(x)
#else
#define EXP2F(x) exp2f(x)
#endif
#if __has_builtin(__builtin_amdgcn_logf)
#define LOG2F(x) __builtin_amdgcn_logf(x)   // v_log_f32 computes log2
#else
#define LOG2F(x) __log2f(x)
#endif

// ---------------------------------------------------------------------------
// Kernel F: fill Ds with bf16(BIG). Padding cells then self-propagate BIG in
// the DP (replaces per-step active-masking: -3 VALU/step on the chain).
// ---------------------------------------------------------------------------
__global__ __launch_bounds__(256) void dtw_fill(uint4* __restrict__ p, int n4) {
  const uint4 v = make_uint4(BIGP, BIGP, BIGP, BIGP);
  for (int i = blockIdx.x * 256 + threadIdx.x; i < n4; i += gridDim.x * 256)
    p[i] = v;
}

// ---------------------------------------------------------------------------
// Kernel A: skewed bf16 distance matrix (valid cells only; rest stays BIG).
//   Ds[b][s][t] = bf16( SINV * ||x[b,t,:] - y[b,s-sk(t),:]||^2 ),
//   sk(t) = t + (t>>6)*LAG.  LDS-staged coalesced stores.
// ---------------------------------------------------------------------------
__global__ __launch_bounds__(256) void dtw_dist_skew(const float* __restrict__ x,
                                                     const float* __restrict__ y,
                                                     __hip_bfloat16* __restrict__ Ds) {
  __shared__ float xs[128][65];
  __shared__ float ys[128][65];
  __shared__ __hip_bfloat16 sm[128][130];   // staged bf16 tile (il, jl)
  const int b  = blockIdx.z;
  const int i0 = blockIdx.y * 128;
  const int j0 = blockIdx.x * 128;
  const int tid = threadIdx.x;

  const float* xb = x + ((size_t)b * N_ + i0) * Dm_;
  const float* yb = y + ((size_t)b * M_ + j0) * Dm_;
#pragma unroll
  for (int r = 0; r < 8; ++r) {
    int v4 = tid + r * 256;
    int row = v4 >> 4, c4 = (v4 & 15) * 4;
    float4 xv = *(const float4*)(xb + (size_t)row * Dm_ + c4);
    float4 yv = *(const float4*)(yb + (size_t)row * Dm_ + c4);
    xs[row][c4 + 0] = xv.x; xs[row][c4 + 1] = xv.y;
    xs[row][c4 + 2] = xv.z; xs[row][c4 + 3] = xv.w;
    ys[row][c4 + 0] = yv.x; ys[row][c4 + 1] = yv.y;
    ys[row][c4 + 2] = yv.z; ys[row][c4 + 3] = yv.w;
  }
  __syncthreads();

  const int ty = tid >> 4, tx = tid & 15;
  float acc[8][8];
#pragma unroll
  for (int e = 0; e < 8; ++e)
#pragma unroll
    for (int f = 0; f < 8; ++f) acc[e][f] = 0.f;

#pragma unroll 4
  for (int k = 0; k < Dm_; ++k) {
    float xa[8], yv[8];
#pragma unroll
    for (int e = 0; e < 8; ++e) xa[e] = xs[ty * 8 + e][k];
#pragma unroll
    for (int f = 0; f < 8; ++f) yv[f] = ys[tx * 8 + f][k];
#pragma unroll
    for (int e = 0; e < 8; ++e)
#pragma unroll
      for (int f = 0; f < 8; ++f) {
        float t = xa[e] - yv[f];
        acc[e][f] = fmaf(t, t, acc[e][f]);
      }
  }

  // stage bf16 tile in LDS
#pragma unroll
  for (int e = 0; e < 8; ++e)
#pragma unroll
    for (int f = 0; f < 8; ++f)
      sm[ty * 8 + e][tx * 8 + f] = __float2bfloat16(acc[e][f] * SINV);
  __syncthreads();

  // coalesced skewed store: two 64-row halves with constant skew per half.
  const int W0 = i0 >> 6;
  const int Sbase = i0 + j0 + LAG * W0;     // smallest s touched by this tile
  __hip_bfloat16* base = Ds + (size_t)b * SPAD * N_;
  const int g = tid >> 6, lane = tid & 63;  // 4 groups x 64 lanes
  for (int pass = 0; pass < 68; ++pass) {
    const int v = pass * 4 + g;             // s-span of tile = 254 + LAG = 270
    const int s = Sbase + v;
#pragma unroll
    for (int h = 0; h < 2; ++h) {
      const int u  = i0 + v - LAG * h;      // = s - j0 - LAG*(W0+h)
      const int lo = max(i0 + 64 * h, u - 127);
      const int hi = min(i0 + 64 * h + 63, u);
      const int t  = lo + lane;
      if (t <= hi) base[(size_t)s * N_ + t] = sm[t - i0][u - t];
    }
  }
}

// ---------------------------------------------------------------------------
// Kernel B (dtw_dp5): skewed-pipeline DP, 1 batch/block, 64 blocks.
// Lane t owns row i=t+1; at step s computes column j = s - skew + 1,
// skew = t + wave*LAG.  No masking: BIG-padded D self-propagates BIG.
//   nb (=A) = R'[i-1][j]   : lane t-1's r @ s-1 via DPP wave_shr:1
//   r       = R'[i][j-1]   : own previous value
//   C       = R'[i-1][j-1] : previous nb
// 4-phase epoch templates: ring LDS offsets are compile-time immediates;
// cur/nxt load buffers swap roles at compile time (no copies).
// Ring: 8 rows x 64 slots; phase p writes {16p..16p+15}, reads
// {16p+47..16p+62} (mod 64) — disjoint within an epoch, values 1-2 barriers
// old. Row 7 is never written: wave 0 reads BIG.
// ---------------------------------------------------------------------------
template <int PH, bool TAIL>
__device__ __forceinline__ void dp_epoch(const ushort* __restrict__ colrow,
                                         ushort (&cur)[16], ushort (&nxt)[16],
                                         float (&ring)[8 * RING],
                                         int rd_base, int wr_base, bool pub,
                                         float& A, float& r) {
  if (!TAIL) {
#pragma unroll
    for (int k = 0; k < 16; ++k) nxt[k] = colrow[(size_t)k * N_];
  }
  float rv[16];
#pragma unroll
  for (int k = 0; k < 16; ++k)
    rv[k] = ring[rd_base + ((PH * 16 + k - 17) & (RING - 1))];

  float rbuf[16];
  constexpr int KMAX = TAIL ? 15 : 16;
#pragma unroll
  for (int k = 0; k < KMAX; ++k) {
    const int nbi = __builtin_amdgcn_update_dpp(__float_as_int(rv[k]),
                    __float_as_int(r), 0x138 /*wave_shr:1*/, 0xF, 0xF, false);
    const float nb = __int_as_float(nbi);
    const float C = A;                       // R'[i-1][j-1]
    A = nb;                                  // R'[i-1][j]
    const float mn = fminf(fminf(nb, r), C); // -> v_min3_f32
    const float e  = (EXP2F(mn - nb) + EXP2F(mn - r)) + EXP2F(mn - C);
    const float d  = __uint_as_float((uint)cur[k] << 16);
    r = (d + mn) - LOG2F(e);
    rbuf[k] = r;
  }
  if (!TAIL) {
    if (pub) {
#pragma unroll
      for (int k = 0; k < 16; ++k)
        ring[wr_base + ((PH * 16 + k) & (RING - 1))] = rbuf[k];
    }
    __syncthreads();
  }
}

__global__ __launch_bounds__(512, 1) void dtw_dp5(const ushort* __restrict__ Ds,
                                                  float* __restrict__ wv) {
  const int b    = blockIdx.x;
  const int t    = threadIdx.x;   // 0..511
  const int w    = t >> 6;        // wave 0..7
  const int lane = t & 63;

  __shared__ float ring[8 * RING];
  ring[t] = BIGF;                 // 512 = 8*RING exactly
  __syncthreads();

  const ushort* col = Ds + (size_t)b * SPAD * N_ + t;
  const int rd_base = ((w + 7) & 7) * RING;   // wave w reads row w-1 (w=0 -> 7)
  const bool pub    = (lane == 63) && (w < 7);
  const int wr_base = w * RING;

  float A = (t == 0) ? 0.0f : BIGF;  // becomes C=R'[0][0]=0 at lane 0's step 0
  float r = BIGF;                    // own previous value (R'[i][0] = BIG)

  ushort bufA[16], bufB[16];
#pragma unroll
  for (int k = 0; k < 16; ++k) bufA[k] = col[(size_t)k * N_];  // rows 0..15

  const ushort* cr = col + (size_t)16 * N_;   // next-rows base
#pragma unroll 1
  for (int g = 0; g < 17; ++g) {              // 68 epochs
    dp_epoch<0, false>(cr, bufA, bufB, ring, rd_base, wr_base, pub, A, r); cr += (size_t)16 * N_;
    dp_epoch<1, false>(cr, bufB, bufA, ring, rd_base, wr_base, pub, A, r); cr += (size_t)16 * N_;
    dp_epoch<2, false>(cr, bufA, bufB, ring, rd_base, wr_base, pub, A, r); cr += (size_t)16 * N_;
    dp_epoch<3, false>(cr, bufB, bufA, ring, rd_base, wr_base, pub, A, r); cr += (size_t)16 * N_;
  }
  // blk 68 (phase 0) loads rows 1104..1119; blk 69 (phase 1) loads 1120..1135
  dp_epoch<0, false>(cr, bufA, bufB, ring, rd_base, wr_base, pub, A, r); cr += (size_t)16 * N_;
  dp_epoch<1, false>(cr, bufB, bufA, ring, rd_base, wr_base, pub, A, r);
  // tail: steps 1120..1134 (phase 2), no loads/publish/barrier
  dp_epoch<2, true>(nullptr, bufA, bufB, ring, rd_base, wr_base, pub, A, r);

  if (t == N_ - 1) wv[b] = EXP2F(-0.1f * r);  // w = exp(-R) = 2^(-gamma*R')
}

// ---------------------------------------------------------------------------
// Kernel C: out = x * w[b], full-grid elementwise (float4).
// ---------------------------------------------------------------------------
__global__ __launch_bounds__(256) void dtw_mul_kernel(const float* __restrict__ x,
                                                      const float* __restrict__ wv,
                                                      float* __restrict__ out) {
  const int idx = blockIdx.x * 256 + threadIdx.x;   // float4 index
  const int b = idx >> 13;                          // 8192 float4 per batch
  const float w = wv[b];
  float4 v = ((const float4*)x)[idx];
  v.x *= w; v.y *= w; v.z *= w; v.w *= w;
  ((float4*)out)[idx] = v;
}

// ---------------------------------------------------------------------------
// Fallback (no workspace): barrier-per-step fused DP. Slow but correct.
// ---------------------------------------------------------------------------
__global__ __launch_bounds__(512) void dtw_dp_fused(const float* __restrict__ x,
                                                    const float* __restrict__ y,
                                                    float* __restrict__ out) {
  __shared__ float v[3][516];
  const int b = blockIdx.x;
  const int t = threadIdx.x;
  const int i = t + 1;
  if (t == 0) { v[0][0] = 0.f; v[1][0] = BIGF; v[2][0] = BIGF; }
  v[0][i] = BIGF;
  v[1][i] = BIGF;
  float xr[Dm_];
  const float* xrow = x + ((size_t)b * N_ + t) * Dm_;
#pragma unroll
  for (int k = 0; k < Dm_; ++k) xr[k] = xrow[k];
  __syncthreads();
  int cur = 2, m1 = 1, m2 = 0;
  const float GLN2 = 0.069314718055994531f;
  for (int p = 2; p <= N_ + M_; ++p) {
    const int j = p - i;
    const bool valid = (j >= 1) && (j <= M_);
    float d = 0.f;
    if (valid) {
      const float* yr = y + ((size_t)b * M_ + (j - 1)) * Dm_;
      float a = 0.f;
#pragma unroll
      for (int k = 0; k < Dm_; ++k) { float u = xr[k] - yr[k]; a = fmaf(u, u, a); }
      d = a;
    }
    const float a  = v[m1][i - 1];
    const float bb = v[m1][i];
    const float c  = v[m2][i - 1];
    const float mn = fminf(fminf(a, bb), c);
    const float s = exp2f((mn - a) * SINV) + exp2f((mn - bb) * SINV) +
                    exp2f((mn - c) * SINV);
    const float rr = valid ? (d + mn - GLN2 * log2f(s)) : BIGF;
    v[cur][i] = rr;
    if (t == 0) v[cur][0] = BIGF;
    __syncthreads();
    const int tmp = m2; m2 = m1; m1 = cur; cur = tmp;
  }
  const float dist = v[(N_ + M_) % 3][N_];
  const float wsc = expf(-dist);
  const float* xb = x + (size_t)b * N_ * Dm_;
  float* ob = out + (size_t)b * N_ * Dm_;
#pragma unroll
  for (int e = 0; e < (N_ * Dm_) / 512; ++e) {
    const int idx = e * 512 + t;
    ob[idx] = xb[idx] * wsc;
  }
}

// ---------------------------------------------------------------------------
extern "C" void kernel_launch(void* const* d_in, const int* in_sizes, int n_in,
                              void* d_out, int out_size, void* d_ws, size_t ws_size,
                              hipStream_t stream) {
  const float* x = (const float*)d_in[0];
  const float* y = (const float*)d_in[1];
  float* out = (float*)d_out;

  const size_t needS = (size_t)B_ * SPAD * N_ * 2;   // 74,448,896 B
  const int mul_grid = (B_ * N_ * Dm_ / 4) / 256;    // 2048

  if (ws_size >= needS + 4096) {
    __hip_bfloat16* Dsb = (__hip_bfloat16*)d_ws;
    float* wvp = (float*)((char*)d_ws + needS);
    dtw_fill<<<dim3(2048), dim3(256), 0, stream>>>((uint4*)d_ws, (int)(needS / 16));
    dim3 g(M_ / 128, N_ / 128, B_);
    dtw_dist_skew<<<g, dim3(256), 0, stream>>>(x, y, Dsb);
    dtw_dp5<<<dim3(B_), dim3(512), 0, stream>>>((const ushort*)Dsb, wvp);
    dtw_mul_kernel<<<dim3(mul_grid), dim3(256), 0, stream>>>(x, wvp, out);
  } else {
    dtw_dp_fused<<<dim3(B_), dim3(512), 0, stream>>>(x, y, out);
  }
}

// Round 9
// 159.073 us; speedup vs baseline: 3.2511x; 1.3995x over previous
//
#include <hip/hip_runtime.h>
#include <hip/hip_bf16.h>

#define B_   64
#define N_   512
#define M_   512
#define Dm_  64
#define BIGF 1e30f
#define BIGP 0x714A714Au            // 2x bf16(~1.01e30) packed
// gamma = 0.1; scaled units R' = R / (gamma*ln2):
//   r' = d' + mn' - log2(2^(mn'-a') + 2^(mn'-b') + 2^(mn'-c'))
#define SINV 14.426950408889634f    // 1/(gamma*ln2)
#define LAG  16                     // inter-wave lag = barrier period
#define RING 64                     // slots per boundary row (4 phases x 16)
#define SPAD 1136                   // step rows 0..1135; last live step = 1134

#if __has_builtin(__builtin_amdgcn_exp2f)
#define EXP2F(x) __builtin_amdgcn_exp2f(x)
#else
#define EXP2F(x) exp2f(x)
#endif
#if __has_builtin(__builtin_amdgcn_logf)
#define LOG2F(x) __builtin_amdgcn_logf(x)   // v_log_f32 computes log2
#else
#define LOG2F(x) __log2f(x)
#endif

typedef __attribute__((ext_vector_type(8))) short bf8_t;   // 8 bf16 (4 VGPRs)
typedef __attribute__((ext_vector_type(4))) float f32x4;

static __device__ __forceinline__ ushort f2bf(float f) {   // RNE f32->bf16
  uint u = __float_as_uint(f);
  u += 0x7fff + ((u >> 16) & 1);
  return (ushort)(u >> 16);
}

// ---------------------------------------------------------------------------
// Kernel F: fill Ds with bf16(BIG). Padding cells self-propagate BIG in the
// DP (replaces per-step active-masking).
// ---------------------------------------------------------------------------
__global__ __launch_bounds__(256) void dtw_fill(uint4* __restrict__ p, int n4) {
  const uint4 v = make_uint4(BIGP, BIGP, BIGP, BIGP);
  for (int i = blockIdx.x * 256 + threadIdx.x; i < n4; i += gridDim.x * 256)
    p[i] = v;
}

// ---------------------------------------------------------------------------
// Kernel A (MFMA): skewed bf16 distance matrix.
//   D[i][j] = ||x_i||^2 + ||y_j||^2 - 2 x_i.y_j  via bf16 MFMA NT-GEMM.
//   Ds[b][s][t] = bf16(SINV * D[t][s-sk(t)]), sk(t) = t + (t>>6)*LAG.
// 256 thr / 4 waves; 128x128 tile; each wave one 64x64 quadrant (32 MFMAs).
// LDS: X/Y bf16 tiles [128][72] (stride 144B = 36 banks: 2-way = free);
// output staged in sm[128][136] OVERLAYING X/Y (union keeps LDS ~37.9KB,
// 4 blocks/CU); norms in f32 alongside. Store phase = R8's coalesced skew.
// ---------------------------------------------------------------------------
__global__ __launch_bounds__(256) void dtw_dist_mfma(const float* __restrict__ x,
                                                     const float* __restrict__ y,
                                                     ushort* __restrict__ Ds) {
  __shared__ __align__(16) char ldsbuf[36864 + 1024];
  ushort* Xs = (ushort*)ldsbuf;                       // [128][72]
  ushort* Ys = (ushort*)(ldsbuf + 18432);             // [128][72]
  ushort* SM = (ushort*)ldsbuf;                       // [128][136] (overlay)
  float*  XN = (float*)(ldsbuf + 36864);              // [128]
  float*  YN = (float*)(ldsbuf + 37376);              // [128]

  const int b  = blockIdx.z;
  const int i0 = blockIdx.y * 128;
  const int j0 = blockIdx.x * 128;
  const int tid = threadIdx.x;

  // ---- load phase: f32 -> bf16 staging + f32 norms --------------------------
  {
    const int row = tid >> 1;              // 0..127
    const int hc  = (tid & 1) * 32;        // col half
    const float4* xr = (const float4*)(x + ((size_t)b * N_ + i0 + row) * Dm_ + hc);
    const float4* yr = (const float4*)(y + ((size_t)b * M_ + j0 + row) * Dm_ + hc);
    float sx = 0.f, sy = 0.f;
#pragma unroll
    for (int q = 0; q < 8; ++q) {
      float4 v = xr[q];
      sx += v.x * v.x + v.y * v.y + v.z * v.z + v.w * v.w;
      ushort4 h = make_ushort4(f2bf(v.x), f2bf(v.y), f2bf(v.z), f2bf(v.w));
      *(ushort4*)&Xs[row * 72 + hc + q * 4] = h;
      float4 u = yr[q];
      sy += u.x * u.x + u.y * u.y + u.z * u.z + u.w * u.w;
      ushort4 g = make_ushort4(f2bf(u.x), f2bf(u.y), f2bf(u.z), f2bf(u.w));
      *(ushort4*)&Ys[row * 72 + hc + q * 4] = g;
    }
    sx += __shfl_xor(sx, 1);
    sy += __shfl_xor(sy, 1);
    if (!(tid & 1)) { XN[row] = sx; YN[row] = sy; }
  }
  __syncthreads();

  // ---- MFMA phase -----------------------------------------------------------
  const int w = tid >> 6, lane = tid & 63;
  const int wm = w >> 1, wn = w & 1;       // 64x64 quadrant
  const int lr = lane & 15, lk = lane >> 4;

  f32x4 acc[4][4];
#pragma unroll
  for (int fm = 0; fm < 4; ++fm)
#pragma unroll
    for (int fn = 0; fn < 4; ++fn) acc[fm][fn] = (f32x4){0.f, 0.f, 0.f, 0.f};

#pragma unroll
  for (int kk = 0; kk < 2; ++kk) {
    bf8_t a[4], bv[4];
#pragma unroll
    for (int f = 0; f < 4; ++f) {
      a[f]  = *(const bf8_t*)&Xs[(wm * 64 + f * 16 + lr) * 72 + kk * 32 + lk * 8];
      bv[f] = *(const bf8_t*)&Ys[(wn * 64 + f * 16 + lr) * 72 + kk * 32 + lk * 8];
    }
#pragma unroll
    for (int fm = 0; fm < 4; ++fm)
#pragma unroll
      for (int fn = 0; fn < 4; ++fn)
        acc[fm][fn] = __builtin_amdgcn_mfma_f32_16x16x32_bf16(a[fm], bv[fn],
                                                              acc[fm][fn], 0, 0, 0);
  }
  __syncthreads();   // all X/Y reads done before SM overlay writes

  // ---- epilogue: D = xn + yn - 2G, scale, bf16, stage in SM -----------------
#pragma unroll
  for (int fm = 0; fm < 4; ++fm) {
#pragma unroll
    for (int q = 0; q < 4; ++q) {
      const int il = wm * 64 + fm * 16 + lk * 4 + q;
      const float xa = SINV * XN[il];
#pragma unroll
      for (int fn = 0; fn < 4; ++fn) {
        const int jl = wn * 64 + fn * 16 + lr;
        const float v = xa + fmaf(-2.f * SINV, acc[fm][fn][q], SINV * YN[jl]);
        SM[il * 136 + jl] = f2bf(v);
      }
    }
  }
  __syncthreads();

  // ---- coalesced skewed store (two 64-row halves, constant skew per half) ---
  const int W0 = i0 >> 6;
  const int Sbase = i0 + j0 + LAG * W0;
  ushort* gbase = Ds + (size_t)b * SPAD * N_;
  for (int pass = 0; pass < 68; ++pass) {
    const int v = pass * 4 + w;            // s-span of tile = 271
    const int s = Sbase + v;
#pragma unroll
    for (int h = 0; h < 2; ++h) {
      const int u  = i0 + v - LAG * h;
      const int lo = max(i0 + 64 * h, u - 127);
      const int hi = min(i0 + 64 * h + 63, u);
      const int t  = lo + lane;
      if (t <= hi) gbase[(size_t)s * N_ + t] = SM[(t - i0) * 136 + (u - t)];
    }
  }
}

// ---------------------------------------------------------------------------
// Kernel B (dtw_dp5): skewed-pipeline DP, 1 batch/block, 64 blocks.
// Lane t owns row i=t+1; at step s computes column j = s - skew + 1,
// skew = t + wave*LAG.  No masking: BIG-padded D self-propagates BIG.
// 4-phase epoch templates: ring LDS offsets are compile-time immediates;
// cur/nxt load buffers swap roles at compile time (no copies).
// ---------------------------------------------------------------------------
template <int PH, bool TAIL>
__device__ __forceinline__ void dp_epoch(const ushort* __restrict__ colrow,
                                         ushort (&cur)[16], ushort (&nxt)[16],
                                         float (&ring)[8 * RING],
                                         int rd_base, int wr_base, bool pub,
                                         float& A, float& r) {
  if (!TAIL) {
#pragma unroll
    for (int k = 0; k < 16; ++k) nxt[k] = colrow[(size_t)k * N_];
  }
  float rv[16];
#pragma unroll
  for (int k = 0; k < 16; ++k)
    rv[k] = ring[rd_base + ((PH * 16 + k - 17) & (RING - 1))];

  float rbuf[16];
  constexpr int KMAX = TAIL ? 15 : 16;
#pragma unroll
  for (int k = 0; k < KMAX; ++k) {
    const int nbi = __builtin_amdgcn_update_dpp(__float_as_int(rv[k]),
                    __float_as_int(r), 0x138 /*wave_shr:1*/, 0xF, 0xF, false);
    const float nb = __int_as_float(nbi);
    const float C = A;                       // R'[i-1][j-1]
    A = nb;                                  // R'[i-1][j]
    const float mn = fminf(fminf(nb, r), C); // -> v_min3_f32
    const float e  = (EXP2F(mn - nb) + EXP2F(mn - r)) + EXP2F(mn - C);
    const float d  = __uint_as_float((uint)cur[k] << 16);
    r = (d + mn) - LOG2F(e);
    rbuf[k] = r;
  }
  if (!TAIL) {
    if (pub) {
#pragma unroll
      for (int k = 0; k < 16; ++k)
        ring[wr_base + ((PH * 16 + k) & (RING - 1))] = rbuf[k];
    }
    __syncthreads();
  }
}

__global__ __launch_bounds__(512, 1) void dtw_dp5(const ushort* __restrict__ Ds,
                                                  float* __restrict__ wv) {
  const int b    = blockIdx.x;
  const int t    = threadIdx.x;   // 0..511
  const int w    = t >> 6;        // wave 0..7
  const int lane = t & 63;

  __shared__ float ring[8 * RING];
  ring[t] = BIGF;                 // 512 = 8*RING exactly
  __syncthreads();

  const ushort* col = Ds + (size_t)b * SPAD * N_ + t;
  const int rd_base = ((w + 7) & 7) * RING;   // wave w reads row w-1 (w=0 -> 7)
  const bool pub    = (lane == 63) && (w < 7);
  const int wr_base = w * RING;

  float A = (t == 0) ? 0.0f : BIGF;  // becomes C=R'[0][0]=0 at lane 0's step 0
  float r = BIGF;                    // own previous value (R'[i][0] = BIG)

  ushort bufA[16], bufB[16];
#pragma unroll
  for (int k = 0; k < 16; ++k) bufA[k] = col[(size_t)k * N_];  // rows 0..15

  const ushort* cr = col + (size_t)16 * N_;   // next-rows base
#pragma unroll 1
  for (int g = 0; g < 17; ++g) {              // 68 epochs
    dp_epoch<0, false>(cr, bufA, bufB, ring, rd_base, wr_base, pub, A, r); cr += (size_t)16 * N_;
    dp_epoch<1, false>(cr, bufB, bufA, ring, rd_base, wr_base, pub, A, r); cr += (size_t)16 * N_;
    dp_epoch<2, false>(cr, bufA, bufB, ring, rd_base, wr_base, pub, A, r); cr += (size_t)16 * N_;
    dp_epoch<3, false>(cr, bufB, bufA, ring, rd_base, wr_base, pub, A, r); cr += (size_t)16 * N_;
  }
  dp_epoch<0, false>(cr, bufA, bufB, ring, rd_base, wr_base, pub, A, r); cr += (size_t)16 * N_;
  dp_epoch<1, false>(cr, bufB, bufA, ring, rd_base, wr_base, pub, A, r);
  // tail: steps 1120..1134 (phase 2), no loads/publish/barrier
  dp_epoch<2, true>(nullptr, bufA, bufB, ring, rd_base, wr_base, pub, A, r);

  if (t == N_ - 1) wv[b] = EXP2F(-0.1f * r);  // w = exp(-R) = 2^(-gamma*R')
}

// ---------------------------------------------------------------------------
// Kernel C: out = x * w[b], full-grid elementwise (float4).
// ---------------------------------------------------------------------------
__global__ __launch_bounds__(256) void dtw_mul_kernel(const float* __restrict__ x,
                                                      const float* __restrict__ wv,
                                                      float* __restrict__ out) {
  const int idx = blockIdx.x * 256 + threadIdx.x;   // float4 index
  const int b = idx >> 13;                          // 8192 float4 per batch
  const float w = wv[b];
  float4 v = ((const float4*)x)[idx];
  v.x *= w; v.y *= w; v.z *= w; v.w *= w;
  ((float4*)out)[idx] = v;
}

// ---------------------------------------------------------------------------
// Fallback (no workspace): barrier-per-step fused DP. Slow but correct.
// ---------------------------------------------------------------------------
__global__ __launch_bounds__(512) void dtw_dp_fused(const float* __restrict__ x,
                                                    const float* __restrict__ y,
                                                    float* __restrict__ out) {
  __shared__ float v[3][516];
  const int b = blockIdx.x;
  const int t = threadIdx.x;
  const int i = t + 1;
  if (t == 0) { v[0][0] = 0.f; v[1][0] = BIGF; v[2][0] = BIGF; }
  v[0][i] = BIGF;
  v[1][i] = BIGF;
  float xr[Dm_];
  const float* xrow = x + ((size_t)b * N_ + t) * Dm_;
#pragma unroll
  for (int k = 0; k < Dm_; ++k) xr[k] = xrow[k];
  __syncthreads();
  int cur = 2, m1 = 1, m2 = 0;
  const float GLN2 = 0.069314718055994531f;
  for (int p = 2; p <= N_ + M_; ++p) {
    const int j = p - i;
    const bool valid = (j >= 1) && (j <= M_);
    float d = 0.f;
    if (valid) {
      const float* yr = y + ((size_t)b * M_ + (j - 1)) * Dm_;
      float a = 0.f;
#pragma unroll
      for (int k = 0; k < Dm_; ++k) { float u = xr[k] - yr[k]; a = fmaf(u, u, a); }
      d = a;
    }
    const float a  = v[m1][i - 1];
    const float bb = v[m1][i];
    const float c  = v[m2][i - 1];
    const float mn = fminf(fminf(a, bb), c);
    const float s = exp2f((mn - a) * SINV) + exp2f((mn - bb) * SINV) +
                    exp2f((mn - c) * SINV);
    const float rr = valid ? (d + mn - GLN2 * log2f(s)) : BIGF;
    v[cur][i] = rr;
    if (t == 0) v[cur][0] = BIGF;
    __syncthreads();
    const int tmp = m2; m2 = m1; m1 = cur; cur = tmp;
  }
  const float dist = v[(N_ + M_) % 3][N_];
  const float wsc = expf(-dist);
  const float* xb = x + (size_t)b * N_ * Dm_;
  float* ob = out + (size_t)b * N_ * Dm_;
#pragma unroll
  for (int e = 0; e < (N_ * Dm_) / 512; ++e) {
    const int idx = e * 512 + t;
    ob[idx] = xb[idx] * wsc;
  }
}

// ---------------------------------------------------------------------------
extern "C" void kernel_launch(void* const* d_in, const int* in_sizes, int n_in,
                              void* d_out, int out_size, void* d_ws, size_t ws_size,
                              hipStream_t stream) {
  const float* x = (const float*)d_in[0];
  const float* y = (const float*)d_in[1];
  float* out = (float*)d_out;

  const size_t needS = (size_t)B_ * SPAD * N_ * 2;   // 74,448,896 B
  const int mul_grid = (B_ * N_ * Dm_ / 4) / 256;    // 2048

  if (ws_size >= needS + 4096) {
    ushort* Dsb = (ushort*)d_ws;
    float* wvp = (float*)((char*)d_ws + needS);
    dtw_fill<<<dim3(2048), dim3(256), 0, stream>>>((uint4*)d_ws, (int)(needS / 16));
    dim3 g(M_ / 128, N_ / 128, B_);
    dtw_dist_mfma<<<g, dim3(256), 0, stream>>>(x, y, Dsb);
    dtw_dp5<<<dim3(B_), dim3(512), 0, stream>>>(Dsb, wvp);
    dtw_mul_kernel<<<dim3(mul_grid), dim3(256), 0, stream>>>(x, wvp, out);
  } else {
    dtw_dp_fused<<<dim3(B_), dim3(512), 0, stream>>>(x, y, out);
  }
}

// Round 11
// 118.035 us; speedup vs baseline: 4.3814x; 1.3477x over previous
//
#include <hip/hip_runtime.h>
#include <hip/hip_bf16.h>

#define B_   64
#define N_   512
#define M_   512
#define Dm_  64
// gamma = 0.1. Exp-domain DP: S = 2^{-R'}, R' = R/(gamma*ln2).
//   S_new = K * (S_A + S_r + S_C),  K = 2^{-SINV*d}  (precomputed, bf16)
// Impossible paths have S = 0 (replaces BIG); no fill pass needed.
#define SINV 14.426950408889634f    // 1/(gamma*ln2)
#define LAG  16                     // inter-wave lag = barrier period
#define RING 64                     // ring slots per boundary (4 phases x 16)
#define SPAD 1136                   // step rows 0..1135; last live step = 1134
#define T_EXP 24                    // rescale target exponent (headroom both sides)

#if __has_builtin(__builtin_amdgcn_exp2f)
#define EXP2F(x) __builtin_amdgcn_exp2f(x)
#else
#define EXP2F(x) exp2f(x)
#endif
#if __has_builtin(__builtin_amdgcn_logf)
#define LOG2F(x) __builtin_amdgcn_logf(x)   // v_log_f32 computes log2
#else
#define LOG2F(x) __log2f(x)
#endif

typedef __attribute__((ext_vector_type(8))) short bf8_t;   // 8 bf16 (4 VGPRs)
typedef __attribute__((ext_vector_type(4))) float f32x4;

static __device__ __forceinline__ ushort f2bf(float f) {   // RNE f32->bf16
  uint u = __float_as_uint(f);
  u += 0x7fff + ((u >> 16) & 1);
  return (ushort)(u >> 16);
}

template <int CTRL>
static __device__ __forceinline__ float dppmaxf(float m) {
  const int i = __builtin_amdgcn_update_dpp(0, __float_as_int(m), CTRL, 0xF, 0xF, false);
  return fmaxf(m, __int_as_float(i));   // old=0 for invalid lanes: S >= 0, safe
}

// ---------------------------------------------------------------------------
// Kernel A (MFMA): skewed bf16 K-matrix.
//   Ks[b][s][t] = bf16( 2^{-SINV * ||x[b,t,:] - y[b,s-sk(t),:]||^2} ),
//   sk(t) = t + (t>>6)*LAG. Only valid cells written; pads are garbage and
//   masked to 0 at DP load time (0 = impossible path).
// ---------------------------------------------------------------------------
__global__ __launch_bounds__(256) void dtw_dist_mfma(const float* __restrict__ x,
                                                     const float* __restrict__ y,
                                                     ushort* __restrict__ Ds) {
  __shared__ __align__(16) char ldsbuf[36864 + 1024];
  ushort* Xs = (ushort*)ldsbuf;                       // [128][72]
  ushort* Ys = (ushort*)(ldsbuf + 18432);             // [128][72]
  ushort* SM = (ushort*)ldsbuf;                       // [128][136] (overlay)
  float*  XN = (float*)(ldsbuf + 36864);              // [128]
  float*  YN = (float*)(ldsbuf + 37376);              // [128]

  const int b  = blockIdx.z;
  const int i0 = blockIdx.y * 128;
  const int j0 = blockIdx.x * 128;
  const int tid = threadIdx.x;

  // ---- load: f32 -> bf16 staging + f32 norms --------------------------------
  {
    const int row = tid >> 1;              // 0..127
    const int hc  = (tid & 1) * 32;        // col half
    const float4* xr = (const float4*)(x + ((size_t)b * N_ + i0 + row) * Dm_ + hc);
    const float4* yr = (const float4*)(y + ((size_t)b * M_ + j0 + row) * Dm_ + hc);
    float sx = 0.f, sy = 0.f;
#pragma unroll
    for (int q = 0; q < 8; ++q) {
      float4 v = xr[q];
      sx += v.x * v.x + v.y * v.y + v.z * v.z + v.w * v.w;
      ushort4 h = make_ushort4(f2bf(v.x), f2bf(v.y), f2bf(v.z), f2bf(v.w));
      *(ushort4*)&Xs[row * 72 + hc + q * 4] = h;
      float4 u = yr[q];
      sy += u.x * u.x + u.y * u.y + u.z * u.z + u.w * u.w;
      ushort4 g = make_ushort4(f2bf(u.x), f2bf(u.y), f2bf(u.z), f2bf(u.w));
      *(ushort4*)&Ys[row * 72 + hc + q * 4] = g;
    }
    sx += __shfl_xor(sx, 1);
    sy += __shfl_xor(sy, 1);
    if (!(tid & 1)) { XN[row] = sx; YN[row] = sy; }
  }
  __syncthreads();

  // ---- MFMA -----------------------------------------------------------------
  const int w = tid >> 6, lane = tid & 63;
  const int wm = w >> 1, wn = w & 1;       // 64x64 quadrant
  const int lr = lane & 15, lk = lane >> 4;

  f32x4 acc[4][4];
#pragma unroll
  for (int fm = 0; fm < 4; ++fm)
#pragma unroll
    for (int fn = 0; fn < 4; ++fn) acc[fm][fn] = (f32x4){0.f, 0.f, 0.f, 0.f};

#pragma unroll
  for (int kk = 0; kk < 2; ++kk) {
    bf8_t a[4], bv[4];
#pragma unroll
    for (int f = 0; f < 4; ++f) {
      a[f]  = *(const bf8_t*)&Xs[(wm * 64 + f * 16 + lr) * 72 + kk * 32 + lk * 8];
      bv[f] = *(const bf8_t*)&Ys[(wn * 64 + f * 16 + lr) * 72 + kk * 32 + lk * 8];
    }
#pragma unroll
    for (int fm = 0; fm < 4; ++fm)
#pragma unroll
      for (int fn = 0; fn < 4; ++fn)
        acc[fm][fn] = __builtin_amdgcn_mfma_f32_16x16x32_bf16(a[fm], bv[fn],
                                                              acc[fm][fn], 0, 0, 0);
  }
  __syncthreads();   // all X/Y reads done before SM overlay writes

  // ---- epilogue: K = 2^{-SINV*(xn + yn - 2G)}, bf16, stage in SM ------------
#pragma unroll
  for (int fm = 0; fm < 4; ++fm) {
#pragma unroll
    for (int q = 0; q < 4; ++q) {
      const int il = wm * 64 + fm * 16 + lk * 4 + q;
      const float xa = SINV * XN[il];
#pragma unroll
      for (int fn = 0; fn < 4; ++fn) {
        const int jl = wn * 64 + fn * 16 + lr;
        const float dp = xa + fmaf(-2.f * SINV, acc[fm][fn][q], SINV * YN[jl]);
        SM[il * 136 + jl] = f2bf(EXP2F(-dp));
      }
    }
  }
  __syncthreads();

  // ---- coalesced skewed store (two 64-row halves, constant skew per half) ---
  const int W0 = i0 >> 6;
  const int Sbase = i0 + j0 + LAG * W0;
  ushort* gbase = Ds + (size_t)b * SPAD * N_;
  for (int pass = 0; pass < 68; ++pass) {
    const int v = pass * 4 + w;
    const int s = Sbase + v;
#pragma unroll
    for (int h = 0; h < 2; ++h) {
      const int u  = i0 + v - LAG * h;
      const int lo = max(i0 + 64 * h, u - 127);
      const int hi = min(i0 + 64 * h + 63, u);
      const int t  = lo + lane;
      if (t <= hi) gbase[(size_t)s * N_ + t] = SM[(t - i0) * 136 + (u - t)];
    }
  }
}

// ---------------------------------------------------------------------------
// Kernel B (dtw_dp6): exp-domain skewed-pipeline DP. Lane t owns row i=t+1;
// step s computes column j = s - skew + 1, skew = t + wave*LAG.
//   S_new = K * (S_A + S_r + S_C)   -- no transcendentals on the chain.
// Block-uniform power-of-2 rescale per epoch: wave-max of rbuf[7] (6 DPP-max)
// -> LDS wmax[parity][w]; next epoch all waves derive the same f = 2^{T-e},
// apply to state and consumed ring values (rv[0] crosses two boundaries ->
// f_prev*f). ktot accumulates log2 of the cumulative scale.
// ---------------------------------------------------------------------------
template <int PH, bool TAIL>
__device__ __forceinline__ void dp_epoch6(const ushort* __restrict__ colrow,
                                          float (&dc)[16],
                                          float (&ring)[8 * RING],
                                          float (*wmax)[8],
                                          int rd_base, int wr_base, bool pub,
                                          int w, int lane, int offn,
                                          float& A, float& r, float& fprev, int& ktot) {
  // rescale factor from PREVIOUS epoch's wave maxima (ping-pong slot: parity)
  const float* wm = wmax[(PH ^ 1) & 1];
  float bm = fmaxf(fmaxf(fmaxf(wm[0], wm[1]), fmaxf(wm[2], wm[3])),
                   fmaxf(fmaxf(wm[4], wm[5]), fmaxf(wm[6], wm[7])));
  int kE = T_EXP + 127 - (int)(__float_as_uint(bm) >> 23);
  kE = kE < -126 ? -126 : (kE > 126 ? 126 : kE);
  const float f = __uint_as_float((uint)(kE + 127) << 23);
  const float ff = fprev * f;     // rv[0] was published 2 boundaries ago
  fprev = f; ktot += kE;
  A *= f; r *= f;

  float rv[16];
#pragma unroll
  for (int k = 0; k < 16; ++k)
    rv[k] = ring[rd_base + ((PH * 16 + k - 17) & (RING - 1))] * (k == 0 ? ff : f);

  ushort nx[16];
  if (!TAIL) {
#pragma unroll
    for (int k = 0; k < 16; ++k) nx[k] = colrow[(size_t)k * N_];   // raw, in flight
  }

  float rbuf[16];
  constexpr int KMAX = TAIL ? 15 : 16;
#pragma unroll
  for (int k = 0; k < KMAX; ++k) {
    const int nbi = __builtin_amdgcn_update_dpp(__float_as_int(rv[k]),
                    __float_as_int(r), 0x138 /*wave_shr:1*/, 0xF, 0xF, false);
    const float nb = __int_as_float(nbi);
    const float C = A;                       // S of R'[i-1][j-1]
    A = nb;                                  // S of R'[i-1][j]
    r = dc[k] * ((nb + r) + C);              // K * (S_A + S_r + S_C)
    rbuf[k] = r;
  }
  if (!TAIL) {
    // wave max of rbuf[7] (mid-epoch sample; staleness covered by T_EXP headroom)
    float m = rbuf[7];
    m = dppmaxf<0x111>(m); m = dppmaxf<0x112>(m);
    m = dppmaxf<0x114>(m); m = dppmaxf<0x118>(m);
    m = dppmaxf<0x142>(m); m = dppmaxf<0x143>(m);   // lane 63 has full 64-lane max
    if (lane == 63) wmax[PH & 1][w] = m;
    if (pub) {
#pragma unroll
      for (int k = 0; k < 16; ++k)
        ring[wr_base + ((PH * 16 + k) & (RING - 1))] = rbuf[k];
    }
    __syncthreads();
    // convert+mask next epoch's K (loads issued at epoch start: latency hidden)
#pragma unroll
    for (int k = 0; k < 16; ++k)
      dc[k] = ((uint)(offn + k) < 512u) ? __uint_as_float((uint)nx[k] << 16) : 0.f;
  }
}

__global__ __launch_bounds__(512, 1) void dtw_dp6(const ushort* __restrict__ Ds,
                                                  const float* __restrict__ x,
                                                  float* __restrict__ out) {
  const int b    = blockIdx.x;
  const int t    = threadIdx.x;   // 0..511
  const int w    = t >> 6;        // wave 0..7
  const int lane = t & 63;
  const int skew = t + w * LAG;

  __shared__ float ring[8 * RING];
  __shared__ float wmax[2][8];
  __shared__ float wbc;
  ring[t] = 0.f;                  // 0 == S(BIG): impossible path
  if (t < 16) wmax[t >> 3][t & 7] = __uint_as_float((uint)(T_EXP + 127) << 23);
  __syncthreads();

  const ushort* col = Ds + (size_t)b * SPAD * N_ + t;
  const int rd_base = ((w + 7) & 7) * RING;   // wave w reads row w-1 (w=0 -> 7: 0)
  const bool pub    = (lane == 63) && (w < 7);
  const int wr_base = w * RING;

  float A = (t == 0) ? 1.0f : 0.f;   // S(R'[0][0]=0)=1 seeds lane 0's first step
  float r = 0.f;                     // S(R'[i][0]=BIG)=0
  float fprev = 1.0f;
  int ktot = 0;

  float dc[16];
#pragma unroll
  for (int k = 0; k < 16; ++k) {
    const ushort raw = col[(size_t)k * N_];
    dc[k] = ((uint)(k - skew) < 512u) ? __uint_as_float((uint)raw << 16) : 0.f;
  }

  const ushort* cr = col + (size_t)16 * N_;
  int offn = 16 - skew;
#pragma unroll 1
  for (int g = 0; g < 17; ++g) {      // epochs 0..67
    dp_epoch6<0, false>(cr, dc, ring, wmax, rd_base, wr_base, pub, w, lane, offn, A, r, fprev, ktot); cr += (size_t)16 * N_; offn += 16;
    dp_epoch6<1, false>(cr, dc, ring, wmax, rd_base, wr_base, pub, w, lane, offn, A, r, fprev, ktot); cr += (size_t)16 * N_; offn += 16;
    dp_epoch6<2, false>(cr, dc, ring, wmax, rd_base, wr_base, pub, w, lane, offn, A, r, fprev, ktot); cr += (size_t)16 * N_; offn += 16;
    dp_epoch6<3, false>(cr, dc, ring, wmax, rd_base, wr_base, pub, w, lane, offn, A, r, fprev, ktot); cr += (size_t)16 * N_; offn += 16;
  }
  dp_epoch6<0, false>(cr, dc, ring, wmax, rd_base, wr_base, pub, w, lane, offn, A, r, fprev, ktot); cr += (size_t)16 * N_; offn += 16;
  dp_epoch6<1, false>(cr, dc, ring, wmax, rd_base, wr_base, pub, w, lane, offn, A, r, fprev, ktot); cr += (size_t)16 * N_; offn += 16;
  // tail: steps 1120..1134, no loads/publish/barrier
  dp_epoch6<2, true>(cr, dc, ring, wmax, rd_base, wr_base, pub, w, lane, offn, A, r, fprev, ktot);

  // R' = ktot - log2(s_hat);  w = 2^{-0.1 R'} = 2^{0.1 (log2(s_hat) - ktot)}
  if (t == N_ - 1) wbc = EXP2F(0.1f * (LOG2F(r) - (float)ktot));
  __syncthreads();
  const float wsc = wbc;

  const float4* x4 = (const float4*)(x + (size_t)b * N_ * Dm_);
  float4* o4 = (float4*)(out + (size_t)b * N_ * Dm_);
#pragma unroll
  for (int e = 0; e < 16; ++e) {
    float4 v = x4[e * 512 + t];
    v.x *= wsc; v.y *= wsc; v.z *= wsc; v.w *= wsc;
    o4[e * 512 + t] = v;
  }
}

// ---------------------------------------------------------------------------
// Fallback (no workspace): barrier-per-step fused DP. Slow but correct.
// ---------------------------------------------------------------------------
__global__ __launch_bounds__(512) void dtw_dp_fused(const float* __restrict__ x,
                                                    const float* __restrict__ y,
                                                    float* __restrict__ out) {
  __shared__ float v[3][516];
  const int b = blockIdx.x;
  const int t = threadIdx.x;
  const int i = t + 1;
  const float BIGF = 1e30f;
  if (t == 0) { v[0][0] = 0.f; v[1][0] = BIGF; v[2][0] = BIGF; }
  v[0][i] = BIGF;
  v[1][i] = BIGF;
  float xr[Dm_];
  const float* xrow = x + ((size_t)b * N_ + t) * Dm_;
#pragma unroll
  for (int k = 0; k < Dm_; ++k) xr[k] = xrow[k];
  __syncthreads();
  int cur = 2, m1 = 1, m2 = 0;
  const float GLN2 = 0.069314718055994531f;
  for (int p = 2; p <= N_ + M_; ++p) {
    const int j = p - i;
    const bool valid = (j >= 1) && (j <= M_);
    float d = 0.f;
    if (valid) {
      const float* yr = y + ((size_t)b * M_ + (j - 1)) * Dm_;
      float a = 0.f;
#pragma unroll
      for (int k = 0; k < Dm_; ++k) { float u = xr[k] - yr[k]; a = fmaf(u, u, a); }
      d = a;
    }
    const float a  = v[m1][i - 1];
    const float bb = v[m1][i];
    const float c  = v[m2][i - 1];
    const float mn = fminf(fminf(a, bb), c);
    const float s = exp2f((mn - a) * SINV) + exp2f((mn - bb) * SINV) +
                    exp2f((mn - c) * SINV);
    const float rr = valid ? (d + mn - GLN2 * log2f(s)) : BIGF;
    v[cur][i] = rr;
    if (t == 0) v[cur][0] = BIGF;
    __syncthreads();
    const int tmp = m2; m2 = m1; m1 = cur; cur = tmp;
  }
  const float dist = v[(N_ + M_) % 3][N_];
  const float wsc = expf(-dist);
  const float* xb = x + (size_t)b * N_ * Dm_;
  float* ob = out + (size_t)b * N_ * Dm_;
#pragma unroll
  for (int e = 0; e < (N_ * Dm_) / 512; ++e) {
    const int idx = e * 512 + t;
    ob[idx] = xb[idx] * wsc;
  }
}

// ---------------------------------------------------------------------------
extern "C" void kernel_launch(void* const* d_in, const int* in_sizes, int n_in,
                              void* d_out, int out_size, void* d_ws, size_t ws_size,
                              hipStream_t stream) {
  const float* x = (const float*)d_in[0];
  const float* y = (const float*)d_in[1];
  float* out = (float*)d_out;

  const size_t needS = (size_t)B_ * SPAD * N_ * 2;   // 74,448,896 B

  if (ws_size >= needS) {
    ushort* Dsb = (ushort*)d_ws;
    dim3 g(M_ / 128, N_ / 128, B_);
    dtw_dist_mfma<<<g, dim3(256), 0, stream>>>(x, y, Dsb);
    dtw_dp6<<<dim3(B_), dim3(512), 0, stream>>>(Dsb, x, out);
  } else {
    dtw_dp_fused<<<dim3(B_), dim3(512), 0, stream>>>(x, y, out);
  }
}

// Round 12
// 107.153 us; speedup vs baseline: 4.8264x; 1.1016x over previous
//
#include <hip/hip_runtime.h>
#include <hip/hip_bf16.h>

#define B_   64
#define N_   512
#define M_   512
#define Dm_  64
// gamma = 0.1. Exp-domain DP: S = 2^{-R'}, R' = R/(gamma*ln2).
//   S_new = K * (S_A + S_r + S_C),  K = 2^{-SINV*d}  (precomputed, bf16)
// Impossible paths have S = 0 (replaces BIG); no fill pass needed.
#define SINV 14.426950408889634f    // 1/(gamma*ln2)
#define LAG  16                     // inter-wave lag = barrier period
#define RING 64                     // ring slots per boundary (4 phases x 16)
#define SPAD 1136                   // step rows 0..1135; last live step = 1134
#define T_EXP 24                    // rescale target exponent

#if __has_builtin(__builtin_amdgcn_exp2f)
#define EXP2F(x) __builtin_amdgcn_exp2f(x)
#else
#define EXP2F(x) exp2f(x)
#endif
#if __has_builtin(__builtin_amdgcn_logf)
#define LOG2F(x) __builtin_amdgcn_logf(x)   // v_log_f32 computes log2
#else
#define LOG2F(x) __log2f(x)
#endif

// Raw barrier: drain LDS only (ring correctness); global loads stay in
// flight across the barrier (no vmcnt(0) — the __syncthreads structural
// drain was the dominant per-epoch cost). "memory" clobber pins ordering.
#define EPOCH_BARRIER() asm volatile("s_waitcnt lgkmcnt(0)\n\ts_barrier" ::: "memory")

typedef __attribute__((ext_vector_type(8))) short bf8_t;   // 8 bf16 (4 VGPRs)
typedef __attribute__((ext_vector_type(4))) float f32x4;

static __device__ __forceinline__ ushort f2bf(float f) {   // RNE f32->bf16
  uint u = __float_as_uint(f);
  u += 0x7fff + ((u >> 16) & 1);
  return (ushort)(u >> 16);
}

template <int CTRL>
static __device__ __forceinline__ float dppmaxf(float m) {
  const int i = __builtin_amdgcn_update_dpp(0, __float_as_int(m), CTRL, 0xF, 0xF, false);
  return fmaxf(m, __int_as_float(i));   // old=0 for invalid lanes: S >= 0, safe
}

// ---------------------------------------------------------------------------
// Kernel A (MFMA): skewed bf16 K-matrix (unchanged from R11).
//   Ks[b][s][t] = bf16( 2^{-SINV * ||x[b,t,:] - y[b,s-sk(t),:]||^2} )
// ---------------------------------------------------------------------------
__global__ __launch_bounds__(256) void dtw_dist_mfma(const float* __restrict__ x,
                                                     const float* __restrict__ y,
                                                     ushort* __restrict__ Ds) {
  __shared__ __align__(16) char ldsbuf[36864 + 1024];
  ushort* Xs = (ushort*)ldsbuf;                       // [128][72]
  ushort* Ys = (ushort*)(ldsbuf + 18432);             // [128][72]
  ushort* SM = (ushort*)ldsbuf;                       // [128][136] (overlay)
  float*  XN = (float*)(ldsbuf + 36864);              // [128]
  float*  YN = (float*)(ldsbuf + 37376);              // [128]

  const int b  = blockIdx.z;
  const int i0 = blockIdx.y * 128;
  const int j0 = blockIdx.x * 128;
  const int tid = threadIdx.x;

  {
    const int row = tid >> 1;
    const int hc  = (tid & 1) * 32;
    const float4* xr = (const float4*)(x + ((size_t)b * N_ + i0 + row) * Dm_ + hc);
    const float4* yr = (const float4*)(y + ((size_t)b * M_ + j0 + row) * Dm_ + hc);
    float sx = 0.f, sy = 0.f;
#pragma unroll
    for (int q = 0; q < 8; ++q) {
      float4 v = xr[q];
      sx += v.x * v.x + v.y * v.y + v.z * v.z + v.w * v.w;
      ushort4 h = make_ushort4(f2bf(v.x), f2bf(v.y), f2bf(v.z), f2bf(v.w));
      *(ushort4*)&Xs[row * 72 + hc + q * 4] = h;
      float4 u = yr[q];
      sy += u.x * u.x + u.y * u.y + u.z * u.z + u.w * u.w;
      ushort4 g = make_ushort4(f2bf(u.x), f2bf(u.y), f2bf(u.z), f2bf(u.w));
      *(ushort4*)&Ys[row * 72 + hc + q * 4] = g;
    }
    sx += __shfl_xor(sx, 1);
    sy += __shfl_xor(sy, 1);
    if (!(tid & 1)) { XN[row] = sx; YN[row] = sy; }
  }
  __syncthreads();

  const int w = tid >> 6, lane = tid & 63;
  const int wm = w >> 1, wn = w & 1;
  const int lr = lane & 15, lk = lane >> 4;

  f32x4 acc[4][4];
#pragma unroll
  for (int fm = 0; fm < 4; ++fm)
#pragma unroll
    for (int fn = 0; fn < 4; ++fn) acc[fm][fn] = (f32x4){0.f, 0.f, 0.f, 0.f};

#pragma unroll
  for (int kk = 0; kk < 2; ++kk) {
    bf8_t a[4], bv[4];
#pragma unroll
    for (int f = 0; f < 4; ++f) {
      a[f]  = *(const bf8_t*)&Xs[(wm * 64 + f * 16 + lr) * 72 + kk * 32 + lk * 8];
      bv[f] = *(const bf8_t*)&Ys[(wn * 64 + f * 16 + lr) * 72 + kk * 32 + lk * 8];
    }
#pragma unroll
    for (int fm = 0; fm < 4; ++fm)
#pragma unroll
      for (int fn = 0; fn < 4; ++fn)
        acc[fm][fn] = __builtin_amdgcn_mfma_f32_16x16x32_bf16(a[fm], bv[fn],
                                                              acc[fm][fn], 0, 0, 0);
  }
  __syncthreads();

#pragma unroll
  for (int fm = 0; fm < 4; ++fm) {
#pragma unroll
    for (int q = 0; q < 4; ++q) {
      const int il = wm * 64 + fm * 16 + lk * 4 + q;
      const float xa = SINV * XN[il];
#pragma unroll
      for (int fn = 0; fn < 4; ++fn) {
        const int jl = wn * 64 + fn * 16 + lr;
        const float dp = xa + fmaf(-2.f * SINV, acc[fm][fn][q], SINV * YN[jl]);
        SM[il * 136 + jl] = f2bf(EXP2F(-dp));
      }
    }
  }
  __syncthreads();

  const int W0 = i0 >> 6;
  const int Sbase = i0 + j0 + LAG * W0;
  ushort* gbase = Ds + (size_t)b * SPAD * N_;
  for (int pass = 0; pass < 68; ++pass) {
    const int v = pass * 4 + w;
    const int s = Sbase + v;
#pragma unroll
    for (int h = 0; h < 2; ++h) {
      const int u  = i0 + v - LAG * h;
      const int lo = max(i0 + 64 * h, u - 127);
      const int hi = min(i0 + 64 * h + 63, u);
      const int t  = lo + lane;
      if (t <= hi) gbase[(size_t)s * N_ + t] = SM[(t - i0) * 136 + (u - t)];
    }
  }
}

// ---------------------------------------------------------------------------
// Kernel B (dtw_dp7): exp-domain DP with raw barriers + 2-deep prefetch +
// half-rate rescale.
// Epoch e (phase PH = e mod 4): issue loads rows 16(e+2) -> nxNew; steps use
// dc (rows 16e); convert nxOld (rows 16(e+1), loaded at e-1, in flight ~2
// epoch bodies) -> dc; LDS-only barrier. Rescale at even phases only:
// with 2-epoch cadence the 17-deep ring reach spans exactly one rescale for
// all slots at even epochs (x f), and only rv[0] at odd epochs crosses the
// previous rescale (x fprev).
// ---------------------------------------------------------------------------
template <int PH, int MODE>   // MODE: 0 = full, 1 = no-load, 2 = tail
__device__ __forceinline__ void dp_epoch7(const ushort* __restrict__ loadbase,
                                          ushort (&nxOld)[16], ushort (&nxNew)[16],
                                          float (&dc)[16],
                                          float (&ring)[8 * RING],
                                          float (*wmax)[8],
                                          int rd_base, int wr_base, bool pub,
                                          int w, int lane, int offn,
                                          float& A, float& r, float& fprev, int& ktot) {
  constexpr bool EVEN = (PH & 1) == 0;
  constexpr bool TAIL = (MODE == 2);
  float f = 1.0f;
  if (EVEN) {
    // rescale from wave-maxima sampled at the previous (odd) epoch
    const float* wm = wmax[PH == 0 ? 1 : 0];
    float bm = fmaxf(fmaxf(fmaxf(wm[0], wm[1]), fmaxf(wm[2], wm[3])),
                     fmaxf(fmaxf(wm[4], wm[5]), fmaxf(wm[6], wm[7])));
    int kE = T_EXP + 127 - (int)(__float_as_uint(bm) >> 23);
    kE = kE < -126 ? -126 : (kE > 126 ? 126 : kE);
    f = __uint_as_float((uint)(kE + 127) << 23);
    fprev = f; ktot += kE;
    A *= f; r *= f;
  }

  float rv[16];
#pragma unroll
  for (int k = 0; k < 16; ++k)
    rv[k] = ring[rd_base + ((PH * 16 + k - 17) & (RING - 1))];
  if (EVEN) {
#pragma unroll
    for (int k = 0; k < 16; ++k) rv[k] *= f;
  } else {
    rv[0] *= fprev;   // published before the last rescale (2-epoch cadence)
  }

  if (MODE == 0) {
#pragma unroll
    for (int k = 0; k < 16; ++k) nxNew[k] = loadbase[(size_t)k * N_];
  }

  float rbuf[16];
  constexpr int KMAX = TAIL ? 15 : 16;
#pragma unroll
  for (int k = 0; k < KMAX; ++k) {
    const float pre = r + A;            // prev-step values: off the new chain
    const int nbi = __builtin_amdgcn_update_dpp(__float_as_int(rv[k]),
                    __float_as_int(r), 0x138 /*wave_shr:1*/, 0xF, 0xF, false);
    const float nb = __int_as_float(nbi);
    A = nb;                             // S of R'[i-1][j-1] for next step
    r = dc[k] * (pre + nb);             // K * (S_A + S_r + S_C)
    rbuf[k] = r;
  }

  if (!TAIL) {
    if (!EVEN) {
      // sample wave max (feeds the rescale at the NEXT even epoch)
      float m = rbuf[7];
      m = dppmaxf<0x111>(m); m = dppmaxf<0x112>(m);
      m = dppmaxf<0x114>(m); m = dppmaxf<0x118>(m);
      m = dppmaxf<0x142>(m); m = dppmaxf<0x143>(m);
      if (lane == 63) wmax[(PH >> 1) & 1][w] = m;
    }
    if (pub) {
#pragma unroll
      for (int k = 0; k < 16; ++k)
        ring[wr_base + ((PH * 16 + k) & (RING - 1))] = rbuf[k];
    }
    // convert next epoch's K (nxOld loaded 1 epoch ago: ~2 bodies in flight)
#pragma unroll
    for (int k = 0; k < 16; ++k)
      dc[k] = ((uint)(offn + k) < 512u) ? __uint_as_float((uint)nxOld[k] << 16) : 0.f;
    EPOCH_BARRIER();
  }
}

__global__ __launch_bounds__(512, 1) void dtw_dp7(const ushort* __restrict__ Ds,
                                                  const float* __restrict__ x,
                                                  float* __restrict__ out) {
  const int b    = blockIdx.x;
  const int t    = threadIdx.x;   // 0..511
  const int w    = t >> 6;        // wave 0..7
  const int lane = t & 63;
  const int skew = t + w * LAG;

  __shared__ float ring[8 * RING];
  __shared__ float wmax[2][8];
  __shared__ float wbc;
  ring[t] = 0.f;                  // 0 == S(BIG): impossible path
  if (t < 16) wmax[t >> 3][t & 7] = __uint_as_float((uint)(T_EXP + 127) << 23);
  __syncthreads();

  const ushort* col = Ds + (size_t)b * SPAD * N_ + t;
  const int rd_base = ((w + 7) & 7) * RING;   // wave w reads row w-1 (w=0 -> 7: 0)
  const bool pub    = (lane == 63) && (w < 7);
  const int wr_base = w * RING;

  float A = (t == 0) ? 1.0f : 0.f;   // S(R'[0][0]=0)=1 seeds lane 0's first step
  float r = 0.f;                     // S(R'[i][0]=BIG)=0
  float fprev = 1.0f;
  int ktot = 0;

  // prologue: rows 0..15 -> bufA (convert now), rows 16..31 -> bufB (in flight)
  ushort bufA[16], bufB[16];
#pragma unroll
  for (int k = 0; k < 16; ++k) bufA[k] = col[(size_t)k * N_];
#pragma unroll
  for (int k = 0; k < 16; ++k) bufB[k] = col[(size_t)(16 + k) * N_];
  float dc[16];
#pragma unroll
  for (int k = 0; k < 16; ++k)
    dc[k] = ((uint)(k - skew) < 512u) ? __uint_as_float((uint)bufA[k] << 16) : 0.f;

  const ushort* cr = col + (size_t)32 * N_;   // load base: rows 16(e+2)
  int offn = 16 - skew;                        // conversion range for rows 16(e+1)
#pragma unroll 1
  for (int g = 0; g < 17; ++g) {               // epochs 0..67
    dp_epoch7<0, 0>(cr, bufB, bufA, dc, ring, wmax, rd_base, wr_base, pub, w, lane, offn, A, r, fprev, ktot); cr += (size_t)16 * N_; offn += 16;
    dp_epoch7<1, 0>(cr, bufA, bufB, dc, ring, wmax, rd_base, wr_base, pub, w, lane, offn, A, r, fprev, ktot); cr += (size_t)16 * N_; offn += 16;
    dp_epoch7<2, 0>(cr, bufB, bufA, dc, ring, wmax, rd_base, wr_base, pub, w, lane, offn, A, r, fprev, ktot); cr += (size_t)16 * N_; offn += 16;
    dp_epoch7<3, 0>(cr, bufA, bufB, dc, ring, wmax, rd_base, wr_base, pub, w, lane, offn, A, r, fprev, ktot); cr += (size_t)16 * N_; offn += 16;
  }
  // epoch 68 (PH0, full): loads rows 1120..1135 (last valid)
  dp_epoch7<0, 0>(cr, bufB, bufA, dc, ring, wmax, rd_base, wr_base, pub, w, lane, offn, A, r, fprev, ktot); offn += 16;
  // epoch 69 (PH1, no-load): converts rows 1120 -> dc for the tail
  dp_epoch7<1, 1>(nullptr, bufA, bufB, dc, ring, wmax, rd_base, wr_base, pub, w, lane, offn, A, r, fprev, ktot);
  // tail: steps 1120..1134 (PH2, 15 steps, no loads/publish/barrier)
  dp_epoch7<2, 2>(nullptr, bufB, bufA, dc, ring, wmax, rd_base, wr_base, pub, w, lane, offn, A, r, fprev, ktot);

  // R' = ktot - log2(s_hat);  w = 2^{0.1 (log2(s_hat) - ktot)}
  if (t == N_ - 1) wbc = EXP2F(0.1f * (LOG2F(r) - (float)ktot));
  __syncthreads();
  const float wsc = wbc;

  const float4* x4 = (const float4*)(x + (size_t)b * N_ * Dm_);
  float4* o4 = (float4*)(out + (size_t)b * N_ * Dm_);
#pragma unroll
  for (int e = 0; e < 16; ++e) {
    float4 v = x4[e * 512 + t];
    v.x *= wsc; v.y *= wsc; v.z *= wsc; v.w *= wsc;
    o4[e * 512 + t] = v;
  }
}

// ---------------------------------------------------------------------------
// Fallback (no workspace): barrier-per-step fused DP. Slow but correct.
// ---------------------------------------------------------------------------
__global__ __launch_bounds__(512) void dtw_dp_fused(const float* __restrict__ x,
                                                    const float* __restrict__ y,
                                                    float* __restrict__ out) {
  __shared__ float v[3][516];
  const int b = blockIdx.x;
  const int t = threadIdx.x;
  const int i = t + 1;
  const float BIGF = 1e30f;
  if (t == 0) { v[0][0] = 0.f; v[1][0] = BIGF; v[2][0] = BIGF; }
  v[0][i] = BIGF;
  v[1][i] = BIGF;
  float xr[Dm_];
  const float* xrow = x + ((size_t)b * N_ + t) * Dm_;
#pragma unroll
  for (int k = 0; k < Dm_; ++k) xr[k] = xrow[k];
  __syncthreads();
  int cur = 2, m1 = 1, m2 = 0;
  const float GLN2 = 0.069314718055994531f;
  for (int p = 2; p <= N_ + M_; ++p) {
    const int j = p - i;
    const bool valid = (j >= 1) && (j <= M_);
    float d = 0.f;
    if (valid) {
      const float* yr = y + ((size_t)b * M_ + (j - 1)) * Dm_;
      float a = 0.f;
#pragma unroll
      for (int k = 0; k < Dm_; ++k) { float u = xr[k] - yr[k]; a = fmaf(u, u, a); }
      d = a;
    }
    const float a  = v[m1][i - 1];
    const float bb = v[m1][i];
    const float c  = v[m2][i - 1];
    const float mn = fminf(fminf(a, bb), c);
    const float s = exp2f((mn - a) * SINV) + exp2f((mn - bb) * SINV) +
                    exp2f((mn - c) * SINV);
    const float rr = valid ? (d + mn - GLN2 * log2f(s)) : BIGF;
    v[cur][i] = rr;
    if (t == 0) v[cur][0] = BIGF;
    __syncthreads();
    const int tmp = m2; m2 = m1; m1 = cur; cur = tmp;
  }
  const float dist = v[(N_ + M_) % 3][N_];
  const float wsc = expf(-dist);
  const float* xb = x + (size_t)b * N_ * Dm_;
  float* ob = out + (size_t)b * N_ * Dm_;
#pragma unroll
  for (int e = 0; e < (N_ * Dm_) / 512; ++e) {
    const int idx = e * 512 + t;
    ob[idx] = xb[idx] * wsc;
  }
}

// ---------------------------------------------------------------------------
extern "C" void kernel_launch(void* const* d_in, const int* in_sizes, int n_in,
                              void* d_out, int out_size, void* d_ws, size_t ws_size,
                              hipStream_t stream) {
  const float* x = (const float*)d_in[0];
  const float* y = (const float*)d_in[1];
  float* out = (float*)d_out;

  const size_t needS = (size_t)B_ * SPAD * N_ * 2;   // 74,448,896 B

  if (ws_size >= needS) {
    ushort* Dsb = (ushort*)d_ws;
    dim3 g(M_ / 128, N_ / 128, B_);
    dtw_dist_mfma<<<g, dim3(256), 0, stream>>>(x, y, Dsb);
    dtw_dp7<<<dim3(B_), dim3(512), 0, stream>>>(Dsb, x, out);
  } else {
    dtw_dp_fused<<<dim3(B_), dim3(512), 0, stream>>>(x, y, out);
  }
}

// Round 13
// 87.640 us; speedup vs baseline: 5.9010x; 1.2226x over previous
//
#include <hip/hip_runtime.h>
#include <hip/hip_bf16.h>

#define B_   64
#define N_   512
#define M_   512
#define Dm_  64
// gamma = 0.1. Exp-domain DP: S = 2^{-R'}, R' = R/(gamma*ln2).
//   S_new = K * (S_A + S_r + S_C),  K = 2^{-SINV*d}  (precomputed, bf16)
// Impossible paths have S = 0; pads garbage, masked at convert time.
#define SINV 14.426950408889634f    // 1/(gamma*ln2)
#define LAG  16                     // inter-wave lag = barrier period
#define RING 64                     // ring slots per boundary (4 phases x 16)
#define SPAD 1136                   // 71 epochs x 16 steps; last live step 1134
#define G_   71                     // SPAD/16
#define T_EXP 24                    // rescale target exponent

#if __has_builtin(__builtin_amdgcn_exp2f)
#define EXP2F(x) __builtin_amdgcn_exp2f(x)
#else
#define EXP2F(x) exp2f(x)
#endif
#if __has_builtin(__builtin_amdgcn_logf)
#define LOG2F(x) __builtin_amdgcn_logf(x)   // v_log_f32 computes log2
#else
#define LOG2F(x) __log2f(x)
#endif

// LDS-only barrier: global loads stay in flight across it.
#define EPOCH_BARRIER() asm volatile("s_waitcnt lgkmcnt(0)\n\ts_barrier" ::: "memory")

typedef __attribute__((ext_vector_type(8))) short bf8_t;   // 8 bf16 (4 VGPRs)
typedef __attribute__((ext_vector_type(4))) float f32x4;

static __device__ __forceinline__ ushort f2bf(float f) {   // RNE f32->bf16
  uint u = __float_as_uint(f);
  u += 0x7fff + ((u >> 16) & 1);
  return (ushort)(u >> 16);
}

template <int CTRL>
static __device__ __forceinline__ float dppmaxf(float m) {
  const int i = __builtin_amdgcn_update_dpp(0, __float_as_int(m), CTRL, 0xF, 0xF, false);
  return fmaxf(m, __int_as_float(i));   // old=0: S >= 0, safe
}

// ---------------------------------------------------------------------------
// Kernel A (MFMA): K-matrix in packed-epoch layout.
//   Ds[b][g][t][k] = bf16( 2^{-SINV*||x[b,t]-y[b,s-sk(t)]||^2} ), s=16g+k,
//   sk(t) = t + 16*(t>>6). Valid cells only; pads garbage (masked in DP).
// ---------------------------------------------------------------------------
__global__ __launch_bounds__(256) void dtw_dist_mfma(const float* __restrict__ x,
                                                     const float* __restrict__ y,
                                                     ushort* __restrict__ Ds) {
  __shared__ __align__(16) char ldsbuf[36864 + 1024];
  ushort* Xs = (ushort*)ldsbuf;                       // [128][72]
  ushort* Ys = (ushort*)(ldsbuf + 18432);             // [128][72]
  ushort* SM = (ushort*)ldsbuf;                       // [128][136] (overlay)
  float*  XN = (float*)(ldsbuf + 36864);              // [128]
  float*  YN = (float*)(ldsbuf + 37376);              // [128]

  const int b  = blockIdx.z;
  const int i0 = blockIdx.y * 128;
  const int j0 = blockIdx.x * 128;
  const int tid = threadIdx.x;

  {
    const int row = tid >> 1;
    const int hc  = (tid & 1) * 32;
    const float4* xr = (const float4*)(x + ((size_t)b * N_ + i0 + row) * Dm_ + hc);
    const float4* yr = (const float4*)(y + ((size_t)b * M_ + j0 + row) * Dm_ + hc);
    float sx = 0.f, sy = 0.f;
#pragma unroll
    for (int q = 0; q < 8; ++q) {
      float4 v = xr[q];
      sx += v.x * v.x + v.y * v.y + v.z * v.z + v.w * v.w;
      ushort4 h = make_ushort4(f2bf(v.x), f2bf(v.y), f2bf(v.z), f2bf(v.w));
      *(ushort4*)&Xs[row * 72 + hc + q * 4] = h;
      float4 u = yr[q];
      sy += u.x * u.x + u.y * u.y + u.z * u.z + u.w * u.w;
      ushort4 g = make_ushort4(f2bf(u.x), f2bf(u.y), f2bf(u.z), f2bf(u.w));
      *(ushort4*)&Ys[row * 72 + hc + q * 4] = g;
    }
    sx += __shfl_xor(sx, 1);
    sy += __shfl_xor(sy, 1);
    if (!(tid & 1)) { XN[row] = sx; YN[row] = sy; }
  }
  __syncthreads();

  const int w = tid >> 6, lane = tid & 63;
  const int wm = w >> 1, wn = w & 1;
  const int lr = lane & 15, lk = lane >> 4;

  f32x4 acc[4][4];
#pragma unroll
  for (int fm = 0; fm < 4; ++fm)
#pragma unroll
    for (int fn = 0; fn < 4; ++fn) acc[fm][fn] = (f32x4){0.f, 0.f, 0.f, 0.f};

#pragma unroll
  for (int kk2 = 0; kk2 < 2; ++kk2) {
    bf8_t a[4], bv[4];
#pragma unroll
    for (int f = 0; f < 4; ++f) {
      a[f]  = *(const bf8_t*)&Xs[(wm * 64 + f * 16 + lr) * 72 + kk2 * 32 + lk * 8];
      bv[f] = *(const bf8_t*)&Ys[(wn * 64 + f * 16 + lr) * 72 + kk2 * 32 + lk * 8];
    }
#pragma unroll
    for (int fm = 0; fm < 4; ++fm)
#pragma unroll
      for (int fn = 0; fn < 4; ++fn)
        acc[fm][fn] = __builtin_amdgcn_mfma_f32_16x16x32_bf16(a[fm], bv[fn],
                                                              acc[fm][fn], 0, 0, 0);
  }
  __syncthreads();

#pragma unroll
  for (int fm = 0; fm < 4; ++fm) {
#pragma unroll
    for (int q = 0; q < 4; ++q) {
      const int il = wm * 64 + fm * 16 + lk * 4 + q;
      const float xa = SINV * XN[il];
#pragma unroll
      for (int fn = 0; fn < 4; ++fn) {
        const int jl = wn * 64 + fn * 16 + lr;
        const float dp = xa + fmaf(-2.f * SINV, acc[fm][fn][q], SINV * YN[jl]);
        SM[il * 136 + jl] = f2bf(EXP2F(-dp));
      }
    }
  }
  __syncthreads();

  // ---- packed-epoch store: (t,k)-contiguous, 128 B per wave-store ----------
  // cell (s,t): g=s>>4, k=s&15 -> Ds[((b*G_+g)*N_ + t)*16 + k].
  // Per t-chunk of 16 (const wave-skew), iterate 11 g's covering c in [0,128).
  const int tt = tid >> 4;          // 0..15 (t offset within chunk)
  const int kk = tid & 15;          // k
  ushort* gb = Ds + (size_t)b * G_ * N_ * 16;
#pragma unroll 1
  for (int tq = 0; tq < 8; ++tq) {
    const int Wq = (i0 >> 6) + (tq >> 2);
    const int Cq = i0 + tq * 16 + 16 * Wq + j0;   // s - c for tt=kk=0
    const int t  = i0 + tq * 16 + tt;
    const int g0 = (Cq - 15) >> 4;
#pragma unroll 1
    for (int gg = 0; gg < 11; ++gg) {
      const int g = g0 + gg;
      const int c = 16 * g + kk - tt - Cq;
      if ((unsigned)c < 128u)
        gb[((size_t)g * N_ + t) * 16 + kk] = SM[(t - i0) * 136 + c];
    }
  }
}

// ---------------------------------------------------------------------------
// Kernel B (dtw_dp8): dp7 schedule with vectorized loads/ring.
// Per epoch: 2 x dwordx4 global load (32B contiguous per lane), 4 x
// ds_read_b128 + 1 b32 ring read (uniform-addr broadcast), 4 x ds_write_b128
// publish, pair-unpack convert. Raw LDS barrier; 2-deep load pipeline;
// half-rate rescale (identical semantics to dp7).
// ---------------------------------------------------------------------------
template <int PH, int MODE>   // MODE: 0 = full, 1 = no-load, 2 = tail
__device__ __forceinline__ void dp_epoch8(const ushort* __restrict__ ldp,
                                          uint4 (&nxOld)[2], uint4 (&nxNew)[2],
                                          float (&dc)[16],
                                          float* ring, float (*wmax)[8],
                                          int rd_base, int wr_base, bool pub,
                                          int w, int lane, int offn,
                                          float& A, float& r, float& fprev, int& ktot) {
  constexpr bool EVEN = (PH & 1) == 0;
  constexpr bool TAIL = (MODE == 2);
  float f = 1.0f;
  if (EVEN) {
    const float4* wmp = (const float4*)wmax[PH == 0 ? 1 : 0];
    const float4 wa = wmp[0], wb = wmp[1];
    float bm = fmaxf(fmaxf(fmaxf(wa.x, wa.y), fmaxf(wa.z, wa.w)),
                     fmaxf(fmaxf(wb.x, wb.y), fmaxf(wb.z, wb.w)));
    int kE = T_EXP + 127 - (int)(__float_as_uint(bm) >> 23);
    kE = kE < -126 ? -126 : (kE > 126 ? 126 : kE);
    f = __uint_as_float((uint)(kE + 127) << 23);
    fprev = f; ktot += kE;
    A *= f; r *= f;
  }

  // ring reads: slot(k) = (PH*16 + k - 17) & 63; k=1..15 contiguous 64B-aligned
  const float* rb = ring + rd_base;
  float rv0 = rb[(PH * 16 - 17) & (RING - 1)];
  const float4* rq = (const float4*)(rb + ((PH * 16 - 16) & (RING - 1)));
  float4 q0 = rq[0], q1 = rq[1], q2 = rq[2], q3 = rq[3];
  if (EVEN) {
    rv0 *= f;
    q0.x *= f; q0.y *= f; q0.z *= f; q0.w *= f;
    q1.x *= f; q1.y *= f; q1.z *= f; q1.w *= f;
    q2.x *= f; q2.y *= f; q2.z *= f; q2.w *= f;
    q3.x *= f; q3.y *= f; q3.z *= f;
  } else {
    rv0 *= fprev;   // published before the last rescale (2-epoch cadence)
  }
  float rvk[16] = {rv0, q0.x, q0.y, q0.z, q0.w, q1.x, q1.y, q1.z,
                   q1.w, q2.x, q2.y, q2.z, q2.w, q3.x, q3.y, q3.z};

  if (MODE == 0) {
    const uint4* l4 = (const uint4*)ldp;
    nxNew[0] = l4[0];
    nxNew[1] = l4[1];
  }

  float rbuf[16];
  constexpr int KMAX = TAIL ? 15 : 16;
#pragma unroll
  for (int k = 0; k < KMAX; ++k) {
    const float pre = r + A;            // prev-step values: off the new chain
    const int nbi = __builtin_amdgcn_update_dpp(__float_as_int(rvk[k]),
                    __float_as_int(r), 0x138 /*wave_shr:1*/, 0xF, 0xF, false);
    const float nb = __int_as_float(nbi);
    A = nb;
    r = dc[k] * (pre + nb);             // K * (S_A + S_r + S_C)
    rbuf[k] = r;
  }

  if (!TAIL) {
    if (!EVEN) {
      float m = rbuf[7];
      m = dppmaxf<0x111>(m); m = dppmaxf<0x112>(m);
      m = dppmaxf<0x114>(m); m = dppmaxf<0x118>(m);
      m = dppmaxf<0x142>(m); m = dppmaxf<0x143>(m);
      if (lane == 63) wmax[(PH >> 1) & 1][w] = m;
    }
    if (pub) {   // slots PH*16..PH*16+15: contiguous, 64B-aligned
      float4* wqp = (float4*)(ring + wr_base + PH * 16);
      wqp[0] = make_float4(rbuf[0], rbuf[1], rbuf[2], rbuf[3]);
      wqp[1] = make_float4(rbuf[4], rbuf[5], rbuf[6], rbuf[7]);
      wqp[2] = make_float4(rbuf[8], rbuf[9], rbuf[10], rbuf[11]);
      wqp[3] = make_float4(rbuf[12], rbuf[13], rbuf[14], rbuf[15]);
    }
    // pair-unpack next epoch's K values (loaded 1 epoch ago, ~2 bodies in flight)
    const uint us[8] = {nxOld[0].x, nxOld[0].y, nxOld[0].z, nxOld[0].w,
                        nxOld[1].x, nxOld[1].y, nxOld[1].z, nxOld[1].w};
#pragma unroll
    for (int p = 0; p < 8; ++p) {
      const float lo = __uint_as_float(us[p] << 16);
      const float hi = __uint_as_float(us[p] & 0xffff0000u);
      dc[2 * p]     = ((uint)(offn + 2 * p) < 512u) ? lo : 0.f;
      dc[2 * p + 1] = ((uint)(offn + 2 * p + 1) < 512u) ? hi : 0.f;
    }
    EPOCH_BARRIER();
  }
}

__global__ __launch_bounds__(512, 1) void dtw_dp8(const ushort* __restrict__ Ds,
                                                  const float* __restrict__ x,
                                                  float* __restrict__ out) {
  const int b    = blockIdx.x;
  const int t    = threadIdx.x;   // 0..511
  const int w    = t >> 6;        // wave 0..7
  const int lane = t & 63;
  const int skew = t + w * LAG;

  __shared__ __align__(16) float ring[8 * RING];
  __shared__ __align__(16) float wmax[2][8];
  __shared__ float wbc;
  ring[t] = 0.f;                  // 0 == S(BIG): impossible path
  if (t < 16) wmax[t >> 3][t & 7] = __uint_as_float((uint)(T_EXP + 127) << 23);
  __syncthreads();

  const ushort* colp = Ds + ((size_t)b * G_ * N_ + t) * 16;   // lane's 32B/epoch
  const int rd_base = ((w + 7) & 7) * RING;   // wave w reads row w-1 (w=0 -> 7: 0)
  const bool pub    = (lane == 63) && (w < 7);
  const int wr_base = w * RING;

  float A = (t == 0) ? 1.0f : 0.f;   // S(R'[0][0]=0)=1 seeds lane 0's first step
  float r = 0.f;                     // S(R'[i][0]=BIG)=0
  float fprev = 1.0f;
  int ktot = 0;

  // prologue: epoch0 rows -> bufA (converted), epoch1 rows -> bufB (in flight)
  uint4 bufA[2], bufB[2];
  {
    const uint4* l4 = (const uint4*)colp;
    bufA[0] = l4[0]; bufA[1] = l4[1];
    const uint4* l5 = (const uint4*)(colp + 8192);
    bufB[0] = l5[0]; bufB[1] = l5[1];
  }
  float dc[16];
  {
    const uint us[8] = {bufA[0].x, bufA[0].y, bufA[0].z, bufA[0].w,
                        bufA[1].x, bufA[1].y, bufA[1].z, bufA[1].w};
#pragma unroll
    for (int p = 0; p < 8; ++p) {
      const float lo = __uint_as_float(us[p] << 16);
      const float hi = __uint_as_float(us[p] & 0xffff0000u);
      dc[2 * p]     = ((uint)(2 * p - skew) < 512u) ? lo : 0.f;
      dc[2 * p + 1] = ((uint)(2 * p + 1 - skew) < 512u) ? hi : 0.f;
    }
  }

  const ushort* cr = colp + (size_t)2 * 8192;   // load base: epoch e+2
  int offn = 16 - skew;                         // convert range: epoch e+1
#pragma unroll 1
  for (int g = 0; g < 17; ++g) {                // epochs 0..67
    dp_epoch8<0, 0>(cr, bufB, bufA, dc, ring, wmax, rd_base, wr_base, pub, w, lane, offn, A, r, fprev, ktot); cr += 8192; offn += 16;
    dp_epoch8<1, 0>(cr, bufA, bufB, dc, ring, wmax, rd_base, wr_base, pub, w, lane, offn, A, r, fprev, ktot); cr += 8192; offn += 16;
    dp_epoch8<2, 0>(cr, bufB, bufA, dc, ring, wmax, rd_base, wr_base, pub, w, lane, offn, A, r, fprev, ktot); cr += 8192; offn += 16;
    dp_epoch8<3, 0>(cr, bufA, bufB, dc, ring, wmax, rd_base, wr_base, pub, w, lane, offn, A, r, fprev, ktot); cr += 8192; offn += 16;
  }
  // epoch 68 (PH0): loads epoch-70 rows (last)
  dp_epoch8<0, 0>(cr, bufB, bufA, dc, ring, wmax, rd_base, wr_base, pub, w, lane, offn, A, r, fprev, ktot); offn += 16;
  // epoch 69 (PH1): no load; converts epoch-70 rows -> dc
  dp_epoch8<1, 1>(nullptr, bufA, bufB, dc, ring, wmax, rd_base, wr_base, pub, w, lane, offn, A, r, fprev, ktot);
  // tail epoch 70 (PH2): 15 steps, no loads/publish/barrier
  dp_epoch8<2, 2>(nullptr, bufB, bufA, dc, ring, wmax, rd_base, wr_base, pub, w, lane, offn, A, r, fprev, ktot);

  // R' = ktot - log2(s_hat);  w = 2^{0.1 (log2(s_hat) - ktot)}
  if (t == N_ - 1) wbc = EXP2F(0.1f * (LOG2F(r) - (float)ktot));
  __syncthreads();
  const float wsc = wbc;

  const float4* x4 = (const float4*)(x + (size_t)b * N_ * Dm_);
  float4* o4 = (float4*)(out + (size_t)b * N_ * Dm_);
#pragma unroll
  for (int e = 0; e < 16; ++e) {
    float4 v = x4[e * 512 + t];
    v.x *= wsc; v.y *= wsc; v.z *= wsc; v.w *= wsc;
    o4[e * 512 + t] = v;
  }
}

// ---------------------------------------------------------------------------
// Fallback (no workspace): barrier-per-step fused DP. Slow but correct.
// ---------------------------------------------------------------------------
__global__ __launch_bounds__(512) void dtw_dp_fused(const float* __restrict__ x,
                                                    const float* __restrict__ y,
                                                    float* __restrict__ out) {
  __shared__ float v[3][516];
  const int b = blockIdx.x;
  const int t = threadIdx.x;
  const int i = t + 1;
  const float BIGF = 1e30f;
  if (t == 0) { v[0][0] = 0.f; v[1][0] = BIGF; v[2][0] = BIGF; }
  v[0][i] = BIGF;
  v[1][i] = BIGF;
  float xr[Dm_];
  const float* xrow = x + ((size_t)b * N_ + t) * Dm_;
#pragma unroll
  for (int k = 0; k < Dm_; ++k) xr[k] = xrow[k];
  __syncthreads();
  int cur = 2, m1 = 1, m2 = 0;
  const float GLN2 = 0.069314718055994531f;
  for (int p = 2; p <= N_ + M_; ++p) {
    const int j = p - i;
    const bool valid = (j >= 1) && (j <= M_);
    float d = 0.f;
    if (valid) {
      const float* yr = y + ((size_t)b * M_ + (j - 1)) * Dm_;
      float a = 0.f;
#pragma unroll
      for (int k = 0; k < Dm_; ++k) { float u = xr[k] - yr[k]; a = fmaf(u, u, a); }
      d = a;
    }
    const float a  = v[m1][i - 1];
    const float bb = v[m1][i];
    const float c  = v[m2][i - 1];
    const float mn = fminf(fminf(a, bb), c);
    const float s = exp2f((mn - a) * SINV) + exp2f((mn - bb) * SINV) +
                    exp2f((mn - c) * SINV);
    const float rr = valid ? (d + mn - GLN2 * log2f(s)) : BIGF;
    v[cur][i] = rr;
    if (t == 0) v[cur][0] = BIGF;
    __syncthreads();
    const int tmp = m2; m2 = m1; m1 = cur; cur = tmp;
  }
  const float dist = v[(N_ + M_) % 3][N_];
  const float wsc = expf(-dist);
  const float* xb = x + (size_t)b * N_ * Dm_;
  float* ob = out + (size_t)b * N_ * Dm_;
#pragma unroll
  for (int e = 0; e < (N_ * Dm_) / 512; ++e) {
    const int idx = e * 512 + t;
    ob[idx] = xb[idx] * wsc;
  }
}

// ---------------------------------------------------------------------------
extern "C" void kernel_launch(void* const* d_in, const int* in_sizes, int n_in,
                              void* d_out, int out_size, void* d_ws, size_t ws_size,
                              hipStream_t stream) {
  const float* x = (const float*)d_in[0];
  const float* y = (const float*)d_in[1];
  float* out = (float*)d_out;

  const size_t needS = (size_t)B_ * G_ * N_ * 16 * 2;   // 74,448,896 B

  if (ws_size >= needS) {
    ushort* Dsb = (ushort*)d_ws;
    dim3 g(M_ / 128, N_ / 128, B_);
    dtw_dist_mfma<<<g, dim3(256), 0, stream>>>(x, y, Dsb);
    dtw_dp8<<<dim3(B_), dim3(512), 0, stream>>>(Dsb, x, out);
  } else {
    dtw_dp_fused<<<dim3(B_), dim3(512), 0, stream>>>(x, y, out);
  }
}